// Round 1
// baseline (236.027 us; speedup 1.0000x reference)
//
#include <hip/hip_runtime.h>
#include <hip/hip_bf16.h>

// 12-qubit statevector pipeline, fp32.
// Split path (ws >= ~17MB):
//   enc_kernel : 512 blocks, encode reservoir state -> ws (CX_LONG folded).  [unchanged]
//   proj_split : 2064 blocks, HALF-state LDS (17.5KB) -> 8 blocks/CU.        [new]
//   qhead_kernel: attention last-row + MLP -> d_out.
// Fallback monolithic path if ws is small.

#define PADDED 4224  // 4096 + 4096/32 padding (full-state buffers: enc + mono)
#define HPAD   2112  // 2048 + 2048/32 padding (half-state buffer: proj_split)

#define LDSFENCE asm volatile("s_waitcnt lgkmcnt(0)" ::: "memory")

__device__ __forceinline__ int PD(int j) { return j + (j >> 5); }
__device__ __forceinline__ int PH(int i) { return i + (i >> 5); }

// mode 0: identity; 1: encode ladder+ring read map; 2: CX_LONG; 3: ladder only
__device__ __forceinline__ int mapIdx(int j, int mode) {
  if (mode == 1) { int k = j ^ ((j >> 11) & 1); return k ^ ((k & 0x7FF) << 1); }
  if (mode == 2) { return j ^ ((j & 1) << 11); }
  if (mode == 3) { return j ^ ((j & 0x7FF) << 1); }
  return j;
}

// L0: bits 0-3 local; L1: bits 4-7 local; L2: bits 8-11 local;
// L3: bits 0-3 local with swapped tid nibbles (j8-11=tid0-3, j4-7=tid4-7)
template <int L>
__device__ __forceinline__ int layoutIdx(int tid, int r) {
  if constexpr (L == 0) return (tid << 4) | r;
  else if constexpr (L == 1) return ((tid & 0xF0) << 4) | (r << 4) | (tid & 15);
  else if constexpr (L == 2) return (r << 8) | tid;
  else return ((tid & 15) << 8) | (tid & 0xF0) | r;
}

// drop bit B of a 12-bit element index -> 11-bit half-buffer index
template <int B>
__device__ __forceinline__ int dropbit(int j) {
  constexpr int lo = (1 << B) - 1;
  return (j & lo) | ((j >> 1) & ~lo);
}

template <int L>
__device__ __forceinline__ void ldsRead16(const float* sR, const float* sI, int tid, int mode,
                                          float ar[16], float ai[16]) {
#pragma unroll
  for (int r = 0; r < 16; ++r) {
    int j = layoutIdx<L>(tid, r);
    int a = PD(mapIdx(j, mode));
    ar[r] = sR[a]; ai[r] = sI[a];
  }
}

template <int L>
__device__ __forceinline__ void ldsWrite16(float* sR, float* sI, int tid,
                                           const float ar[16], const float ai[16], int czmask) {
#pragma unroll
  for (int r = 0; r < 16; ++r) {
    int j = layoutIdx<L>(tid, r);
    float vr = ar[r], vi = ai[r];
    if (czmask) {
      float sg = (__popc((j & (j >> 1)) & czmask) & 1) ? -1.0f : 1.0f;
      vr *= sg; vi *= sg;
    }
    int a = PD(j);
    sR[a] = vr; sI[a] = vi;
  }
}

// half-buffer exchange I/O (proj_split)
template <int L, int B>
__device__ __forceinline__ void hWrite16(float* hR, float* hI, int tid,
                                         const float ar[16], const float ai[16]) {
#pragma unroll
  for (int r = 0; r < 16; ++r) {
    int j = layoutIdx<L>(tid, r);
    int a = PH(dropbit<B>(j));
    hR[a] = ar[r]; hI[a] = ai[r];
  }
}

template <int L, int B, int MODE>
__device__ __forceinline__ void hRead16(const float* hR, const float* hI, int tid,
                                        float ar[16], float ai[16]) {
#pragma unroll
  for (int r = 0; r < 16; ++r) {
    int j = mapIdx(layoutIdx<L>(tid, r), MODE);
    int a = PH(dropbit<B>(j));
    ar[r] = hR[a]; ai[r] = hI[a];
  }
}

// 4 U3 gates on local bits 0..3; u00 is real (= cos t/2), exploit u[1]==0.
__device__ __forceinline__ void applyU34(float ar[16], float ai[16], const float (*ut)[8]) {
#pragma unroll
  for (int b = 0; b < 4; ++b) {
    const float* u = ut[b];
    float u00r = u[0];
    float u01r = u[2], u01i = u[3];
    float u10r = u[4], u10i = u[5], u11r = u[6], u11i = u[7];
#pragma unroll
    for (int m = 0; m < 8; ++m) {
      int p0 = ((m >> b) << (b + 1)) | (m & ((1 << b) - 1));
      int p1 = p0 | (1 << b);
      float x0r = ar[p0], x0i = ai[p0], x1r = ar[p1], x1i = ai[p1];
      ar[p0] = u00r * x0r + u01r * x1r - u01i * x1i;
      ai[p0] = u00r * x0i + u01r * x1i + u01i * x1r;
      ar[p1] = u10r * x0r - u10i * x0i + u11r * x1r - u11i * x1i;
      ai[p1] = u10r * x0i + u10i * x0r + u11r * x1i + u11i * x1r;
    }
  }
}

// 4 fused RY+RZ gates, global phase dropped: G = diag(1, e^{i phi}) * RY(theta)
__device__ __forceinline__ void applyRyRz4(float ar[16], float ai[16], const float4* gt) {
#pragma unroll
  for (int b = 0; b < 4; ++b) {
    float4 g = gt[b];
    float c = g.x, s = g.y, zr = g.z, zi = g.w;
#pragma unroll
    for (int m = 0; m < 8; ++m) {
      int p0 = ((m >> b) << (b + 1)) | (m & ((1 << b) - 1));
      int p1 = p0 | (1 << b);
      float x0r = ar[p0], x0i = ai[p0], x1r = ar[p1], x1i = ai[p1];
      float n0r = c * x0r - s * x1r;
      float n0i = c * x0i - s * x1i;
      float wr  = s * x0r + c * x1r;
      float wi  = s * x0i + c * x1i;
      ar[p0] = n0r;              ai[p0] = n0i;
      ar[p1] = wr * zr - wi * zi; ai[p1] = wr * zi + wi * zr;
    }
  }
}

template <int L>
__device__ __forceinline__ void encPass(float* sR, float* sI, int tid, int mode,
                                        const float (*ut)[8], int czmask) {
  float ar[16], ai[16];
  ldsRead16<L>(sR, sI, tid, mode, ar, ai);
  if (mode != 0) __syncthreads();
  applyU34(ar, ai, ut);
  ldsWrite16<L>(sR, sI, tid, ar, ai, czmask);
  __syncthreads();
}

template <int L>
__device__ __forceinline__ void projPass(float* sR, float* sI, int tid, int mode, const float4* gt) {
  float ar[16], ai[16];
  ldsRead16<L>(sR, sI, tid, mode, ar, ai);
  if (mode != 0) __syncthreads();
  applyRyRz4(ar, ai, gt);
  ldsWrite16<L>(sR, sI, tid, ar, ai, 0);
  __syncthreads();
}

// Final projection pass (mono path, L2 layout)
__device__ __forceinline__ void projFinal(const float* sR, const float* sI, int tid,
                                          const float4* gt, float feat[12]) {
  float ar[16], ai[16];
#pragma unroll
  for (int r = 0; r < 16; ++r) {
    int a = PD((r << 8) | tid);
    ar[r] = sR[a]; ai[r] = sI[a];
  }
  applyRyRz4(ar, ai, gt);
  float sp = 0.f, f0 = 0.f, f1 = 0.f, f2 = 0.f, f3 = 0.f;
  int pt = __popc(tid) & 1;
#pragma unroll
  for (int r = 0; r < 16; ++r) {
    float p = ar[r] * ar[r] + ai[r] * ai[r];
    sp += p;
    int tr = r ^ (r << 1); tr ^= (tr << 2);
    f0 += ((pt ^ ((tr >> 3) & 1)) ? -p : p);
    f1 += ((pt ^ ((tr >> 2) & 1)) ? -p : p);
    f2 += ((pt ^ ((tr >> 1) & 1)) ? -p : p);
    f3 += ((pt ^ (tr & 1)) ? -p : p);
  }
  feat[0] = f0; feat[1] = f1; feat[2] = f2; feat[3] = f3;
  int tt = tid ^ (tid << 1); tt ^= (tt << 2); tt ^= (tt << 4);
#pragma unroll
  for (int q = 4; q < 12; ++q)
    feat[q] = ((tt >> (11 - q)) & 1) ? -sp : sp;
}

__device__ __forceinline__ float waveReduce(float v) {
#pragma unroll
  for (int off = 32; off; off >>= 1) v += __shfl_xor(v, off, 64);
  return v;
}

// ---- shared setup helpers ----

__device__ __forceinline__ void buildQtab(float4* qtab, int tid, float x) {
  const float PI = 3.14159265358979323846f;
  const float RS2 = 0.70710678118654752440f;
  if (tid < 12) {
    int i = tid;
    float th = x * PI * (float)(i + 1) / 12.0f;
    float ph = x * PI / (float)(i + 1);
    float s, c;  sincosf(0.5f * th, &s, &c);
    float zi, zr; sincosf(0.5f * ph, &zi, &zr);
    float k0 = (c - s) * RS2, k1 = (c + s) * RS2;
    qtab[i] = make_float4(k0 * zr, -k0 * zi, k1 * zr, k1 * zi);
  }
}

__device__ __forceinline__ void buildUtab(float (*utab)[8], int tid, const float* resp) {
  if (tid >= 64 && tid < 100) {
    int i = tid - 64;
    const float* rp = resp + i * 3;
    float st, ct;  sincosf(0.5f * rp[0], &st, &ct);
    float sp2, cp; sincosf(rp[1], &sp2, &cp);
    float sl, cl;  sincosf(rp[2], &sl, &cl);
    float spl, cpl; sincosf(rp[1] + rp[2], &spl, &cpl);
    float* u = utab[i];
    u[0] = ct;       u[1] = 0.0f;
    u[2] = -cl * st; u[3] = -sl * st;
    u[4] = cp * st;  u[5] = sp2 * st;
    u[6] = cpl * ct; u[7] = spl * ct;
  }
}

__device__ __forceinline__ void initProduct(float* sRe, float* sIm, int tid, const float4* qtab) {
  float pr, pi;
  {
    float4 g = qtab[4];
    int sb = tid & 1;
    pr = sb ? g.z : g.x; pi = sb ? g.w : g.y;
  }
#pragma unroll
  for (int q = 5; q < 12; ++q) {
    float4 g = qtab[q];
    int sb = (tid >> (q - 4)) & 1;
    float fr = sb ? g.z : g.x, fi = sb ? g.w : g.y;
    float nr = pr * fr - pi * fi;
    pi = pr * fi + pi * fr; pr = nr;
  }
  float4 g0 = qtab[0], g1 = qtab[1], g2 = qtab[2], g3 = qtab[3];
  float c01r[4], c01i[4], c23r[4], c23i[4];
#pragma unroll
  for (int i2 = 0; i2 < 4; ++i2) {
    float f0r = (i2 & 1) ? g0.z : g0.x, f0i = (i2 & 1) ? g0.w : g0.y;
    float f1r = (i2 & 2) ? g1.z : g1.x, f1i = (i2 & 2) ? g1.w : g1.y;
    c01r[i2] = f0r * f1r - f0i * f1i; c01i[i2] = f0r * f1i + f0i * f1r;
    float f2r = (i2 & 1) ? g2.z : g2.x, f2i = (i2 & 1) ? g2.w : g2.y;
    float f3r = (i2 & 2) ? g3.z : g3.x, f3i = (i2 & 2) ? g3.w : g3.y;
    c23r[i2] = f2r * f3r - f2i * f3i; c23i[i2] = f2r * f3i + f2i * f3r;
  }
#pragma unroll
  for (int r = 0; r < 16; ++r) {
    float lr = c01r[r & 3] * c23r[r >> 2] - c01i[r & 3] * c23i[r >> 2];
    float li = c01r[r & 3] * c23i[r >> 2] + c01i[r & 3] * c23r[r >> 2];
    int a = PD((tid << 4) | r);
    sRe[a] = pr * lr - pi * li;
    sIm[a] = pr * li + pi * lr;
  }
}

__device__ __forceinline__ void buildPtab(float4* ptab, int tid, const float* hp) {
  if (tid < 24) {
    int k = tid * 2;
    float s, c;  sincosf(0.5f * hp[k], &s, &c);
    float zi, zr; sincosf(hp[k + 1], &zi, &zr);
    ptab[tid] = make_float4(c, s, zr, zi);
  }
}

// ================= SPLIT PATH =================

// Kernel A: encode -> global (unchanged this round; grid-limited to 8 waves/CU).
__global__ __launch_bounds__(256, 2) void enc_kernel(
    const float* __restrict__ seq, const float* __restrict__ resp,
    float* __restrict__ wsStates) {
  __shared__ float sRe[PADDED], sIm[PADDED];
  __shared__ float4 qtab[12];
  __shared__ float utab[36][8];

  const int tid = threadIdx.x;
  const int blk = blockIdx.x;
  const float x = seq[blk];

  buildQtab(qtab, tid, x);
  buildUtab(utab, tid, resp);
  __syncthreads();

  initProduct(sRe, sIm, tid, qtab);
  __syncthreads();

  encPass<0>(sRe, sIm, tid, 1, &utab[0], 0);
  encPass<1>(sRe, sIm, tid, 0, &utab[4], 0);
  encPass<2>(sRe, sIm, tid, 0, &utab[8], 0x555);
  encPass<0>(sRe, sIm, tid, 2, &utab[12], 0);
  encPass<1>(sRe, sIm, tid, 0, &utab[16], 0);
  encPass<2>(sRe, sIm, tid, 0, &utab[20], 0x2AA);
  encPass<0>(sRe, sIm, tid, 2, &utab[24], 0);
  encPass<1>(sRe, sIm, tid, 0, &utab[28], 0);

  {
    float ar[16], ai[16];
    ldsRead16<2>(sRe, sIm, tid, 0, ar, ai);
    applyU34(ar, ai, &utab[32]);
    float* gR = wsStates + (size_t)blk * 8192;
    float* gI = gR + 4096;
#pragma unroll
    for (int r = 0; r < 16; ++r) {
      int j = (r << 8) | tid;
      float sg = (__popc((j & (j >> 1)) & 0x555) & 1) ? -1.0f : 1.0f;
      int g = j ^ ((j & 1) << 11);
      gR[g] = sg * ar[r];
      gI[g] = sg * ai[r];
    }
  }
}

// Kernel B: one projection per block, HALF-state LDS buffer (8 blocks/CU).
//
// Each exchange between layouts moves the full 4096-element state through a
// 2048-entry buffer in two phases, split by an element-index bit B that is a
// per-thread-constant on BOTH the write side and the read side:
//   E1: L0->L1           B=11 (tid7/tid7)  intra-wave per phase (fence only)
//   E2: L1->L2           B=3  (tid3/tid3)
//   E3: L2->L1+ladder    B=0  (tid0/tid0)  (ladder map preserves bit 0)
//   E4: L1->L2           B=3
//   E5: L2->L3           B=7  (tid7/tid7)  intra-wave per phase
// Layer-1 gate order is q4-7, q8-11, q0-3 (commuting) to make E3 phase-matched.
__global__ __launch_bounds__(256, 8) void proj_split(
    const float* __restrict__ wsStates, const float* __restrict__ hparams,
    float* __restrict__ featBase) {
  __shared__ float hRe[HPAD], hIm[HPAD];
  __shared__ float4 ptab[24];
  __shared__ float red[4][12];

  const int tid = threadIdx.x;
  const int bid = blockIdx.x;
  int h, which, s;
  if (bid < 2048) { s = bid >> 2; int pp = bid & 3; h = pp >> 1; which = 1 + (pp & 1); }
  else            { int i = bid - 2048; h = i & 1; s = (((i >> 1) << 6) | 63); which = 0; }
  const int b = s >> 6, t = s & 63;

  buildPtab(ptab, tid, hparams + (h * 3 + which) * 48);

  // coalesced load of the encoded state: thread owns j = 16*tid .. 16*tid+15 (L0)
  float ar[16], ai[16];
  const float4* pR = (const float4*)(wsStates + (size_t)s * 8192 + (tid << 4));
  const float4* pI = (const float4*)(wsStates + (size_t)s * 8192 + 4096 + (tid << 4));
#pragma unroll
  for (int k = 0; k < 4; ++k) {
    float4 vr = pR[k], vi = pI[k];
    ar[4 * k] = vr.x; ar[4 * k + 1] = vr.y; ar[4 * k + 2] = vr.z; ar[4 * k + 3] = vr.w;
    ai[4 * k] = vi.x; ai[4 * k + 1] = vi.y; ai[4 * k + 2] = vi.z; ai[4 * k + 3] = vi.w;
  }
  __syncthreads();  // ptab ready

  const int ph7 = (tid >> 7) & 1;
  const int ph3 = (tid >> 3) & 1;
  const int ph0 = tid & 1;

  // P0: layer-0 q0-3 on regs (L0)
  applyRyRz4(ar, ai, &ptab[0]);

  // E1: write L0 -> read L1; phase tid7; intra-wave within phase
  if (ph7 == 0) { hWrite16<0, 11>(hRe, hIm, tid, ar, ai); LDSFENCE; hRead16<1, 11, 0>(hRe, hIm, tid, ar, ai); }
  __syncthreads();
  if (ph7 == 1) { hWrite16<0, 11>(hRe, hIm, tid, ar, ai); LDSFENCE; hRead16<1, 11, 0>(hRe, hIm, tid, ar, ai); }

  // P2: layer-0 q4-7 (L1)
  applyRyRz4(ar, ai, &ptab[4]);

  // E2: write L1 -> read L2; phase tid3
  __syncthreads();
  if (ph3 == 0) hWrite16<1, 3>(hRe, hIm, tid, ar, ai);
  __syncthreads();
  if (ph3 == 0) hRead16<2, 3, 0>(hRe, hIm, tid, ar, ai);
  __syncthreads();
  if (ph3 == 1) hWrite16<1, 3>(hRe, hIm, tid, ar, ai);
  __syncthreads();
  if (ph3 == 1) hRead16<2, 3, 0>(hRe, hIm, tid, ar, ai);

  // P3: layer-0 q8-11 (L2)
  applyRyRz4(ar, ai, &ptab[8]);

  // E3: write L2 -> read L1 with ladder fold (mode 3); phase tid0
  __syncthreads();
  if (ph0 == 0) hWrite16<2, 0>(hRe, hIm, tid, ar, ai);
  __syncthreads();
  if (ph0 == 0) hRead16<1, 0, 3>(hRe, hIm, tid, ar, ai);
  __syncthreads();
  if (ph0 == 1) hWrite16<2, 0>(hRe, hIm, tid, ar, ai);
  __syncthreads();
  if (ph0 == 1) hRead16<1, 0, 3>(hRe, hIm, tid, ar, ai);

  // P4: layer-1 q4-7 (L1)
  applyRyRz4(ar, ai, &ptab[16]);

  // E4: write L1 -> read L2; phase tid3
  __syncthreads();
  if (ph3 == 0) hWrite16<1, 3>(hRe, hIm, tid, ar, ai);
  __syncthreads();
  if (ph3 == 0) hRead16<2, 3, 0>(hRe, hIm, tid, ar, ai);
  __syncthreads();
  if (ph3 == 1) hWrite16<1, 3>(hRe, hIm, tid, ar, ai);
  __syncthreads();
  if (ph3 == 1) hRead16<2, 3, 0>(hRe, hIm, tid, ar, ai);

  // P5: layer-1 q8-11 (L2)
  applyRyRz4(ar, ai, &ptab[20]);

  // E5: write L2 -> read L3 (swapped-nibble L0); phase tid7; intra-wave
  __syncthreads();
  if (ph7 == 0) { hWrite16<2, 7>(hRe, hIm, tid, ar, ai); LDSFENCE; hRead16<3, 7, 0>(hRe, hIm, tid, ar, ai); }
  __syncthreads();
  if (ph7 == 1) { hWrite16<2, 7>(hRe, hIm, tid, ar, ai); LDSFENCE; hRead16<3, 7, 0>(hRe, hIm, tid, ar, ai); }

  // P6: layer-1 q0-3 (L3) + measurement with trailing-ladder fold.
  // Element j: j0-3=r, j4-7=tid4-7, j8-11=tid0-3. Sign for qubit q = bit (11-q)
  // of prefix-XOR(j).  Bits 0-3: tr(r).  Bit 4..7: tr3 ^ pxor(t4..).  Bit 8..11:
  // tr3 ^ par(t4-7) ^ pxor(t0..).
  applyRyRz4(ar, ai, &ptab[12]);
  float A = 0.f, B2 = 0.f, B1 = 0.f, B0 = 0.f;
#pragma unroll
  for (int r = 0; r < 16; ++r) {
    float p = ar[r] * ar[r] + ai[r] * ai[r];
    int tr = r ^ (r << 1); tr ^= (tr << 2);  // 4-bit prefix-xor of r
    A  += ((tr >> 3) & 1) ? -p : p;
    B2 += ((tr >> 2) & 1) ? -p : p;
    B1 += ((tr >> 1) & 1) ? -p : p;
    B0 += ((tr & 1)      ) ? -p : p;
  }
  int t03p = __popc(tid & 0x0F) & 1;   // parity t0-3
  int t47p = __popc(tid & 0xF0) & 1;   // parity t4-7
  int u4   = (tid >> 4) & 1;
  int u45  = u4 ^ ((tid >> 5) & 1);
  int u456 = u45 ^ ((tid >> 6) & 1);
  int v0   = tid & 1;
  int v01  = v0 ^ ((tid >> 1) & 1);
  int v012 = v01 ^ ((tid >> 2) & 1);
  float feat[12];
  feat[0]  = (t47p ^ t03p) ? -A : A;
  feat[1]  = (t47p ^ v012) ? -A : A;
  feat[2]  = (t47p ^ v01)  ? -A : A;
  feat[3]  = (t47p ^ v0)   ? -A : A;
  feat[4]  = t47p ? -A : A;
  feat[5]  = u456 ? -A : A;
  feat[6]  = u45  ? -A : A;
  feat[7]  = u4   ? -A : A;
  feat[8]  = A;
  feat[9]  = B2;
  feat[10] = B1;
  feat[11] = B0;

#pragma unroll
  for (int q = 0; q < 12; ++q) feat[q] = waveReduce(feat[q]);
  int wid = tid >> 6;
  if ((tid & 63) == 0) {
#pragma unroll
    for (int q = 0; q < 12; ++q) red[wid][q] = feat[q];
  }
  __syncthreads();
  if (tid < 12) {
    float v = red[0][tid] + red[1][tid] + red[2][tid] + red[3][tid];
    float* dst;
    if (which == 1)      dst = featBase + (((h << 3) + b) * 64 + t) * 12;
    else if (which == 2) dst = featBase + 12288 + (((h << 3) + b) * 64 + t) * 12;
    else                 dst = featBase + 24576 + ((h << 3) + b) * 12;
    dst[tid] = v;
  }
}

// ================= MONOLITHIC FALLBACK =================

__global__ __launch_bounds__(256, 2) void qstates_mono(
    const float* __restrict__ seq, const float* __restrict__ resp,
    const float* __restrict__ hparams, float* __restrict__ featBase) {
  __shared__ float sRe[PADDED], sIm[PADDED];
  __shared__ float4 qtab[12];
  __shared__ float utab[36][8];
  __shared__ float4 ptab[24];
  __shared__ float red[4][12];

  const int tid = threadIdx.x;
  const int blk = blockIdx.x;
  const int b = blk >> 6;
  const int t = blk & 63;
  const float x = seq[blk];

  buildQtab(qtab, tid, x);
  buildUtab(utab, tid, resp);
  __syncthreads();
  initProduct(sRe, sIm, tid, qtab);
  __syncthreads();

  for (int l = 0; l < 3; ++l) {
    int czm = (l & 1) ? 0x2AA : 0x555;
    encPass<0>(sRe, sIm, tid, (l == 0) ? 1 : 2, &utab[l * 12], 0);
    encPass<1>(sRe, sIm, tid, 0, &utab[l * 12 + 4], 0);
    encPass<2>(sRe, sIm, tid, 0, &utab[l * 12 + 8], czm);
  }

  float encR[16], encI[16];
#pragma unroll
  for (int r = 0; r < 16; ++r) {
    int j = (tid << 4) | r;
    int a = PD(j ^ ((j & 1) << 11));
    encR[r] = sRe[a]; encI[r] = sIm[a];
  }

  const int nproj = (t == 63) ? 6 : 4;
  for (int pj = 0; pj < nproj; ++pj) {
    int h, which;
    if (pj < 4) { h = pj >> 1; which = (pj & 1) ? 2 : 1; }
    else        { h = pj - 4;  which = 0; }
    buildPtab(ptab, tid, hparams + (h * 3 + which) * 48);
    __syncthreads();

    float ar[16], ai[16];
#pragma unroll
    for (int r = 0; r < 16; ++r) { ar[r] = encR[r]; ai[r] = encI[r]; }
    applyRyRz4(ar, ai, &ptab[0]);
    ldsWrite16<0>(sRe, sIm, tid, ar, ai, 0);
    __syncthreads();
    projPass<1>(sRe, sIm, tid, 0, &ptab[4]);
    projPass<2>(sRe, sIm, tid, 0, &ptab[8]);
    projPass<0>(sRe, sIm, tid, 3, &ptab[12]);
    projPass<1>(sRe, sIm, tid, 0, &ptab[16]);

    float feat[12];
    projFinal(sRe, sIm, tid, &ptab[20], feat);
#pragma unroll
    for (int q = 0; q < 12; ++q) feat[q] = waveReduce(feat[q]);
    int wid = tid >> 6;
    if ((tid & 63) == 0) {
#pragma unroll
      for (int q = 0; q < 12; ++q) red[wid][q] = feat[q];
    }
    __syncthreads();
    if (tid < 12) {
      float v = red[0][tid] + red[1][tid] + red[2][tid] + red[3][tid];
      float* dst;
      if (which == 1)      dst = featBase + (((h << 3) + b) * 64 + t) * 12;
      else if (which == 2) dst = featBase + 12288 + (((h << 3) + b) * 64 + t) * 12;
      else                 dst = featBase + 24576 + ((h << 3) + b) * 12;
      dst[tid] = v;
    }
    __syncthreads();
  }
}

// ================= HEAD =================

__global__ __launch_bounds__(64) void qhead_kernel(
    const float* __restrict__ featBase,
    const float* __restrict__ W1, const float* __restrict__ b1,
    const float* __restrict__ W2, const float* __restrict__ b2,
    float* __restrict__ out) {
  __shared__ float feats[24];
  __shared__ float hdn[48];
  const int b = blockIdx.x;
  const int lane = threadIdx.x;
  const float* Kf = featBase;
  const float* Vf = featBase + 12288;
  const float* Qf = featBase + 24576;
  for (int h = 0; h < 2; ++h) {
    const float* q  = Qf + ((h << 3) + b) * 12;
    const float* kr = Kf + ((((h << 3) + b) << 6) + lane) * 12;
    float dot = 0.f;
#pragma unroll
    for (int d = 0; d < 12; ++d) dot += q[d] * kr[d];
    dot *= 0.288675134594812882f;
    float mx = dot;
#pragma unroll
    for (int off = 32; off; off >>= 1) mx = fmaxf(mx, __shfl_xor(mx, off, 64));
    float e = expf(dot - mx);
    float se = e;
#pragma unroll
    for (int off = 32; off; off >>= 1) se += __shfl_xor(se, off, 64);
    float a = e / se;
    const float* vr = Vf + ((((h << 3) + b) << 6) + lane) * 12;
#pragma unroll
    for (int d = 0; d < 12; ++d) {
      float v = a * vr[d];
#pragma unroll
      for (int off = 32; off; off >>= 1) v += __shfl_xor(v, off, 64);
      if (lane == 0) feats[h * 12 + d] = v;
    }
  }
  __syncthreads();
  if (lane < 48) {
    float acc = b1[lane];
#pragma unroll
    for (int f = 0; f < 24; ++f) acc += feats[f] * W1[f * 48 + lane];
    hdn[lane] = 0.5f * acc * (1.0f + erff(acc * 0.70710678118654752440f));
  }
  __syncthreads();
  if (lane < 4) {
    float acc = b2[lane];
#pragma unroll
    for (int k = 0; k < 48; ++k) acc += hdn[k] * W2[k * 4 + lane];
    out[(b << 2) | lane] = acc;
  }
}

extern "C" void kernel_launch(void* const* d_in, const int* in_sizes, int n_in,
                              void* d_out, int out_size, void* d_ws, size_t ws_size,
                              hipStream_t stream) {
  const float* seq     = (const float*)d_in[0];
  const float* resp    = (const float*)d_in[1];
  const float* hparams = (const float*)d_in[2];
  const float* W1      = (const float*)d_in[3];
  const float* b1      = (const float*)d_in[4];
  const float* W2      = (const float*)d_in[5];
  const float* b2      = (const float*)d_in[6];
  float* out = (float*)d_out;
  float* ws  = (float*)d_ws;

  const size_t needSplit = ((size_t)512 * 8192 + 24768) * sizeof(float);
  if (ws_size >= needSplit) {
    float* wsStates = ws;
    float* featBase = ws + (size_t)512 * 8192;
    hipLaunchKernelGGL(enc_kernel, dim3(512), dim3(256), 0, stream, seq, resp, wsStates);
    hipLaunchKernelGGL(proj_split, dim3(2064), dim3(256), 0, stream, wsStates, hparams, featBase);
    hipLaunchKernelGGL(qhead_kernel, dim3(8), dim3(64), 0, stream, featBase, W1, b1, W2, b2, out);
  } else {
    hipLaunchKernelGGL(qstates_mono, dim3(512), dim3(256), 0, stream, seq, resp, hparams, ws);
    hipLaunchKernelGGL(qhead_kernel, dim3(8), dim3(64), 0, stream, ws, W1, b1, W2, b2, out);
  }
}

// Round 2
// 171.474 us; speedup vs baseline: 1.3765x; 1.3765x over previous
//
#include <hip/hip_runtime.h>
#include <hip/hip_bf16.h>

// 12-qubit statevector pipeline, fp32.
// Split path (ws >= ~17MB):
//   enc_kernel : 512 blocks, encode reservoir state -> ws (CX_LONG folded).
//   proj_split : 2064 blocks, HALF-state LDS (17.5KB).
//                launch_bounds(256,6): VGPR cap 85 avoids the round-1 spill
//                (cap 64 forced the 32-float state to scratch: 500MB HBM traffic).
//                Occupancy = min(LDS: 8 blk/CU, VGPR: >=6 blk/CU).
//   qhead_kernel: attention last-row + MLP -> d_out.
// Fallback monolithic path if ws is small.

#define PADDED 4224  // 4096 + 4096/32 padding (full-state buffers: enc + mono)
#define HPAD   2112  // 2048 + 2048/32 padding (half-state buffer: proj_split)

#define LDSFENCE asm volatile("s_waitcnt lgkmcnt(0)" ::: "memory")

__device__ __forceinline__ int PD(int j) { return j + (j >> 5); }
__device__ __forceinline__ int PH(int i) { return i + (i >> 5); }

// mode 0: identity; 1: encode ladder+ring read map; 2: CX_LONG; 3: ladder only
__device__ __forceinline__ int mapIdx(int j, int mode) {
  if (mode == 1) { int k = j ^ ((j >> 11) & 1); return k ^ ((k & 0x7FF) << 1); }
  if (mode == 2) { return j ^ ((j & 1) << 11); }
  if (mode == 3) { return j ^ ((j & 0x7FF) << 1); }
  return j;
}

// L0: bits 0-3 local; L1: bits 4-7 local; L2: bits 8-11 local;
// L3: bits 0-3 local with swapped tid nibbles (j8-11=tid0-3, j4-7=tid4-7)
template <int L>
__device__ __forceinline__ int layoutIdx(int tid, int r) {
  if constexpr (L == 0) return (tid << 4) | r;
  else if constexpr (L == 1) return ((tid & 0xF0) << 4) | (r << 4) | (tid & 15);
  else if constexpr (L == 2) return (r << 8) | tid;
  else return ((tid & 15) << 8) | (tid & 0xF0) | r;
}

// drop bit B of a 12-bit element index -> 11-bit half-buffer index
template <int B>
__device__ __forceinline__ int dropbit(int j) {
  constexpr int lo = (1 << B) - 1;
  return (j & lo) | ((j >> 1) & ~lo);
}

template <int L>
__device__ __forceinline__ void ldsRead16(const float* sR, const float* sI, int tid, int mode,
                                          float ar[16], float ai[16]) {
#pragma unroll
  for (int r = 0; r < 16; ++r) {
    int j = layoutIdx<L>(tid, r);
    int a = PD(mapIdx(j, mode));
    ar[r] = sR[a]; ai[r] = sI[a];
  }
}

template <int L>
__device__ __forceinline__ void ldsWrite16(float* sR, float* sI, int tid,
                                           const float ar[16], const float ai[16], int czmask) {
#pragma unroll
  for (int r = 0; r < 16; ++r) {
    int j = layoutIdx<L>(tid, r);
    float vr = ar[r], vi = ai[r];
    if (czmask) {
      float sg = (__popc((j & (j >> 1)) & czmask) & 1) ? -1.0f : 1.0f;
      vr *= sg; vi *= sg;
    }
    int a = PD(j);
    sR[a] = vr; sI[a] = vi;
  }
}

// half-buffer exchange I/O (proj_split)
template <int L, int B>
__device__ __forceinline__ void hWrite16(float* hR, float* hI, int tid,
                                         const float ar[16], const float ai[16]) {
#pragma unroll
  for (int r = 0; r < 16; ++r) {
    int j = layoutIdx<L>(tid, r);
    int a = PH(dropbit<B>(j));
    hR[a] = ar[r]; hI[a] = ai[r];
  }
}

template <int L, int B, int MODE>
__device__ __forceinline__ void hRead16(const float* hR, const float* hI, int tid,
                                        float ar[16], float ai[16]) {
#pragma unroll
  for (int r = 0; r < 16; ++r) {
    int j = mapIdx(layoutIdx<L>(tid, r), MODE);
    int a = PH(dropbit<B>(j));
    ar[r] = hR[a]; ai[r] = hI[a];
  }
}

// 4 U3 gates on local bits 0..3; u00 is real (= cos t/2), exploit u[1]==0.
__device__ __forceinline__ void applyU34(float ar[16], float ai[16], const float (*ut)[8]) {
#pragma unroll
  for (int b = 0; b < 4; ++b) {
    const float* u = ut[b];
    float u00r = u[0];
    float u01r = u[2], u01i = u[3];
    float u10r = u[4], u10i = u[5], u11r = u[6], u11i = u[7];
#pragma unroll
    for (int m = 0; m < 8; ++m) {
      int p0 = ((m >> b) << (b + 1)) | (m & ((1 << b) - 1));
      int p1 = p0 | (1 << b);
      float x0r = ar[p0], x0i = ai[p0], x1r = ar[p1], x1i = ai[p1];
      ar[p0] = u00r * x0r + u01r * x1r - u01i * x1i;
      ai[p0] = u00r * x0i + u01r * x1i + u01i * x1r;
      ar[p1] = u10r * x0r - u10i * x0i + u11r * x1r - u11i * x1i;
      ai[p1] = u10r * x0i + u10i * x0r + u11r * x1i + u11i * x1r;
    }
  }
}

// 4 fused RY+RZ gates, global phase dropped: G = diag(1, e^{i phi}) * RY(theta)
__device__ __forceinline__ void applyRyRz4(float ar[16], float ai[16], const float4* gt) {
#pragma unroll
  for (int b = 0; b < 4; ++b) {
    float4 g = gt[b];
    float c = g.x, s = g.y, zr = g.z, zi = g.w;
#pragma unroll
    for (int m = 0; m < 8; ++m) {
      int p0 = ((m >> b) << (b + 1)) | (m & ((1 << b) - 1));
      int p1 = p0 | (1 << b);
      float x0r = ar[p0], x0i = ai[p0], x1r = ar[p1], x1i = ai[p1];
      float n0r = c * x0r - s * x1r;
      float n0i = c * x0i - s * x1i;
      float wr  = s * x0r + c * x1r;
      float wi  = s * x0i + c * x1i;
      ar[p0] = n0r;              ai[p0] = n0i;
      ar[p1] = wr * zr - wi * zi; ai[p1] = wr * zi + wi * zr;
    }
  }
}

template <int L>
__device__ __forceinline__ void encPass(float* sR, float* sI, int tid, int mode,
                                        const float (*ut)[8], int czmask) {
  float ar[16], ai[16];
  ldsRead16<L>(sR, sI, tid, mode, ar, ai);
  if (mode != 0) __syncthreads();
  applyU34(ar, ai, ut);
  ldsWrite16<L>(sR, sI, tid, ar, ai, czmask);
  __syncthreads();
}

template <int L>
__device__ __forceinline__ void projPass(float* sR, float* sI, int tid, int mode, const float4* gt) {
  float ar[16], ai[16];
  ldsRead16<L>(sR, sI, tid, mode, ar, ai);
  if (mode != 0) __syncthreads();
  applyRyRz4(ar, ai, gt);
  ldsWrite16<L>(sR, sI, tid, ar, ai, 0);
  __syncthreads();
}

// Final projection pass (mono path, L2 layout)
__device__ __forceinline__ void projFinal(const float* sR, const float* sI, int tid,
                                          const float4* gt, float feat[12]) {
  float ar[16], ai[16];
#pragma unroll
  for (int r = 0; r < 16; ++r) {
    int a = PD((r << 8) | tid);
    ar[r] = sR[a]; ai[r] = sI[a];
  }
  applyRyRz4(ar, ai, gt);
  float sp = 0.f, f0 = 0.f, f1 = 0.f, f2 = 0.f, f3 = 0.f;
  int pt = __popc(tid) & 1;
#pragma unroll
  for (int r = 0; r < 16; ++r) {
    float p = ar[r] * ar[r] + ai[r] * ai[r];
    sp += p;
    int tr = r ^ (r << 1); tr ^= (tr << 2);
    f0 += ((pt ^ ((tr >> 3) & 1)) ? -p : p);
    f1 += ((pt ^ ((tr >> 2) & 1)) ? -p : p);
    f2 += ((pt ^ ((tr >> 1) & 1)) ? -p : p);
    f3 += ((pt ^ (tr & 1)) ? -p : p);
  }
  feat[0] = f0; feat[1] = f1; feat[2] = f2; feat[3] = f3;
  int tt = tid ^ (tid << 1); tt ^= (tt << 2); tt ^= (tt << 4);
#pragma unroll
  for (int q = 4; q < 12; ++q)
    feat[q] = ((tt >> (11 - q)) & 1) ? -sp : sp;
}

__device__ __forceinline__ float waveReduce(float v) {
#pragma unroll
  for (int off = 32; off; off >>= 1) v += __shfl_xor(v, off, 64);
  return v;
}

// ---- shared setup helpers ----

__device__ __forceinline__ void buildQtab(float4* qtab, int tid, float x) {
  const float PI = 3.14159265358979323846f;
  const float RS2 = 0.70710678118654752440f;
  if (tid < 12) {
    int i = tid;
    float th = x * PI * (float)(i + 1) / 12.0f;
    float ph = x * PI / (float)(i + 1);
    float s, c;  sincosf(0.5f * th, &s, &c);
    float zi, zr; sincosf(0.5f * ph, &zi, &zr);
    float k0 = (c - s) * RS2, k1 = (c + s) * RS2;
    qtab[i] = make_float4(k0 * zr, -k0 * zi, k1 * zr, k1 * zi);
  }
}

__device__ __forceinline__ void buildUtab(float (*utab)[8], int tid, const float* resp) {
  if (tid >= 64 && tid < 100) {
    int i = tid - 64;
    const float* rp = resp + i * 3;
    float st, ct;  sincosf(0.5f * rp[0], &st, &ct);
    float sp2, cp; sincosf(rp[1], &sp2, &cp);
    float sl, cl;  sincosf(rp[2], &sl, &cl);
    float spl, cpl; sincosf(rp[1] + rp[2], &spl, &cpl);
    float* u = utab[i];
    u[0] = ct;       u[1] = 0.0f;
    u[2] = -cl * st; u[3] = -sl * st;
    u[4] = cp * st;  u[5] = sp2 * st;
    u[6] = cpl * ct; u[7] = spl * ct;
  }
}

__device__ __forceinline__ void initProduct(float* sRe, float* sIm, int tid, const float4* qtab) {
  float pr, pi;
  {
    float4 g = qtab[4];
    int sb = tid & 1;
    pr = sb ? g.z : g.x; pi = sb ? g.w : g.y;
  }
#pragma unroll
  for (int q = 5; q < 12; ++q) {
    float4 g = qtab[q];
    int sb = (tid >> (q - 4)) & 1;
    float fr = sb ? g.z : g.x, fi = sb ? g.w : g.y;
    float nr = pr * fr - pi * fi;
    pi = pr * fi + pi * fr; pr = nr;
  }
  float4 g0 = qtab[0], g1 = qtab[1], g2 = qtab[2], g3 = qtab[3];
  float c01r[4], c01i[4], c23r[4], c23i[4];
#pragma unroll
  for (int i2 = 0; i2 < 4; ++i2) {
    float f0r = (i2 & 1) ? g0.z : g0.x, f0i = (i2 & 1) ? g0.w : g0.y;
    float f1r = (i2 & 2) ? g1.z : g1.x, f1i = (i2 & 2) ? g1.w : g1.y;
    c01r[i2] = f0r * f1r - f0i * f1i; c01i[i2] = f0r * f1i + f0i * f1r;
    float f2r = (i2 & 1) ? g2.z : g2.x, f2i = (i2 & 1) ? g2.w : g2.y;
    float f3r = (i2 & 2) ? g3.z : g3.x, f3i = (i2 & 2) ? g3.w : g3.y;
    c23r[i2] = f2r * f3r - f2i * f3i; c23i[i2] = f2r * f3i + f2i * f3r;
  }
#pragma unroll
  for (int r = 0; r < 16; ++r) {
    float lr = c01r[r & 3] * c23r[r >> 2] - c01i[r & 3] * c23i[r >> 2];
    float li = c01r[r & 3] * c23i[r >> 2] + c01i[r & 3] * c23r[r >> 2];
    int a = PD((tid << 4) | r);
    sRe[a] = pr * lr - pi * li;
    sIm[a] = pr * li + pi * lr;
  }
}

__device__ __forceinline__ void buildPtab(float4* ptab, int tid, const float* hp) {
  if (tid < 24) {
    int k = tid * 2;
    float s, c;  sincosf(0.5f * hp[k], &s, &c);
    float zi, zr; sincosf(hp[k + 1], &zi, &zr);
    ptab[tid] = make_float4(c, s, zr, zi);
  }
}

// ================= SPLIT PATH =================

// Kernel A: encode -> global (grid-limited to 2 blocks/CU; next target).
__global__ __launch_bounds__(256, 2) void enc_kernel(
    const float* __restrict__ seq, const float* __restrict__ resp,
    float* __restrict__ wsStates) {
  __shared__ float sRe[PADDED], sIm[PADDED];
  __shared__ float4 qtab[12];
  __shared__ float utab[36][8];

  const int tid = threadIdx.x;
  const int blk = blockIdx.x;
  const float x = seq[blk];

  buildQtab(qtab, tid, x);
  buildUtab(utab, tid, resp);
  __syncthreads();

  initProduct(sRe, sIm, tid, qtab);
  __syncthreads();

  encPass<0>(sRe, sIm, tid, 1, &utab[0], 0);
  encPass<1>(sRe, sIm, tid, 0, &utab[4], 0);
  encPass<2>(sRe, sIm, tid, 0, &utab[8], 0x555);
  encPass<0>(sRe, sIm, tid, 2, &utab[12], 0);
  encPass<1>(sRe, sIm, tid, 0, &utab[16], 0);
  encPass<2>(sRe, sIm, tid, 0, &utab[20], 0x2AA);
  encPass<0>(sRe, sIm, tid, 2, &utab[24], 0);
  encPass<1>(sRe, sIm, tid, 0, &utab[28], 0);

  {
    float ar[16], ai[16];
    ldsRead16<2>(sRe, sIm, tid, 0, ar, ai);
    applyU34(ar, ai, &utab[32]);
    float* gR = wsStates + (size_t)blk * 8192;
    float* gI = gR + 4096;
#pragma unroll
    for (int r = 0; r < 16; ++r) {
      int j = (r << 8) | tid;
      float sg = (__popc((j & (j >> 1)) & 0x555) & 1) ? -1.0f : 1.0f;
      int g = j ^ ((j & 1) << 11);
      gR[g] = sg * ar[r];
      gI[g] = sg * ai[r];
    }
  }
}

// Kernel B: one projection per block, HALF-state LDS buffer.
//
// Each exchange between layouts moves the full 4096-element state through a
// 2048-entry buffer in two phases, split by an element-index bit B that is a
// per-thread-constant on BOTH the write side and the read side:
//   E1: L0->L1           B=11 (tid7/tid7)  intra-wave per phase (fence only)
//   E2: L1->L2           B=3  (tid3/tid3)
//   E3: L2->L1+ladder    B=0  (tid0/tid0)  (ladder map preserves bit 0)
//   E4: L1->L2           B=3
//   E5: L2->L3           B=7  (tid7/tid7)  intra-wave per phase
// Layer-1 gate order is q4-7, q8-11, q0-3 (commuting) to make E3 phase-matched.
//
// launch_bounds(256,6): allocator budget 85 VGPRs. (256,8) (budget 64) spilled
// the 32-float register state to scratch: VGPR_Count=32, 500MB HBM/dispatch, 2x slower.
__global__ __launch_bounds__(256, 6) void proj_split(
    const float* __restrict__ wsStates, const float* __restrict__ hparams,
    float* __restrict__ featBase) {
  __shared__ float hRe[HPAD], hIm[HPAD];
  __shared__ float4 ptab[24];
  __shared__ float red[4][12];

  const int tid = threadIdx.x;
  const int bid = blockIdx.x;
  int h, which, s;
  if (bid < 2048) { s = bid >> 2; int pp = bid & 3; h = pp >> 1; which = 1 + (pp & 1); }
  else            { int i = bid - 2048; h = i & 1; s = (((i >> 1) << 6) | 63); which = 0; }
  const int b = s >> 6, t = s & 63;

  buildPtab(ptab, tid, hparams + (h * 3 + which) * 48);

  // coalesced load of the encoded state: thread owns j = 16*tid .. 16*tid+15 (L0)
  float ar[16], ai[16];
  const float4* pR = (const float4*)(wsStates + (size_t)s * 8192 + (tid << 4));
  const float4* pI = (const float4*)(wsStates + (size_t)s * 8192 + 4096 + (tid << 4));
#pragma unroll
  for (int k = 0; k < 4; ++k) {
    float4 vr = pR[k], vi = pI[k];
    ar[4 * k] = vr.x; ar[4 * k + 1] = vr.y; ar[4 * k + 2] = vr.z; ar[4 * k + 3] = vr.w;
    ai[4 * k] = vi.x; ai[4 * k + 1] = vi.y; ai[4 * k + 2] = vi.z; ai[4 * k + 3] = vi.w;
  }
  __syncthreads();  // ptab ready

  const int ph7 = (tid >> 7) & 1;
  const int ph3 = (tid >> 3) & 1;
  const int ph0 = tid & 1;

  // P0: layer-0 q0-3 on regs (L0)
  applyRyRz4(ar, ai, &ptab[0]);

  // E1: write L0 -> read L1; phase tid7; intra-wave within phase
  if (ph7 == 0) { hWrite16<0, 11>(hRe, hIm, tid, ar, ai); LDSFENCE; hRead16<1, 11, 0>(hRe, hIm, tid, ar, ai); }
  __syncthreads();
  if (ph7 == 1) { hWrite16<0, 11>(hRe, hIm, tid, ar, ai); LDSFENCE; hRead16<1, 11, 0>(hRe, hIm, tid, ar, ai); }

  // P2: layer-0 q4-7 (L1)
  applyRyRz4(ar, ai, &ptab[4]);

  // E2: write L1 -> read L2; phase tid3
  __syncthreads();
  if (ph3 == 0) hWrite16<1, 3>(hRe, hIm, tid, ar, ai);
  __syncthreads();
  if (ph3 == 0) hRead16<2, 3, 0>(hRe, hIm, tid, ar, ai);
  __syncthreads();
  if (ph3 == 1) hWrite16<1, 3>(hRe, hIm, tid, ar, ai);
  __syncthreads();
  if (ph3 == 1) hRead16<2, 3, 0>(hRe, hIm, tid, ar, ai);

  // P3: layer-0 q8-11 (L2)
  applyRyRz4(ar, ai, &ptab[8]);

  // E3: write L2 -> read L1 with ladder fold (mode 3); phase tid0
  __syncthreads();
  if (ph0 == 0) hWrite16<2, 0>(hRe, hIm, tid, ar, ai);
  __syncthreads();
  if (ph0 == 0) hRead16<1, 0, 3>(hRe, hIm, tid, ar, ai);
  __syncthreads();
  if (ph0 == 1) hWrite16<2, 0>(hRe, hIm, tid, ar, ai);
  __syncthreads();
  if (ph0 == 1) hRead16<1, 0, 3>(hRe, hIm, tid, ar, ai);

  // P4: layer-1 q4-7 (L1)
  applyRyRz4(ar, ai, &ptab[16]);

  // E4: write L1 -> read L2; phase tid3
  __syncthreads();
  if (ph3 == 0) hWrite16<1, 3>(hRe, hIm, tid, ar, ai);
  __syncthreads();
  if (ph3 == 0) hRead16<2, 3, 0>(hRe, hIm, tid, ar, ai);
  __syncthreads();
  if (ph3 == 1) hWrite16<1, 3>(hRe, hIm, tid, ar, ai);
  __syncthreads();
  if (ph3 == 1) hRead16<2, 3, 0>(hRe, hIm, tid, ar, ai);

  // P5: layer-1 q8-11 (L2)
  applyRyRz4(ar, ai, &ptab[20]);

  // E5: write L2 -> read L3 (swapped-nibble L0); phase tid7; intra-wave
  __syncthreads();
  if (ph7 == 0) { hWrite16<2, 7>(hRe, hIm, tid, ar, ai); LDSFENCE; hRead16<3, 7, 0>(hRe, hIm, tid, ar, ai); }
  __syncthreads();
  if (ph7 == 1) { hWrite16<2, 7>(hRe, hIm, tid, ar, ai); LDSFENCE; hRead16<3, 7, 0>(hRe, hIm, tid, ar, ai); }

  // P6: layer-1 q0-3 (L3) + measurement with trailing-ladder fold.
  // Element j: j0-3=r, j4-7=tid4-7, j8-11=tid0-3. Sign for qubit q = bit (11-q)
  // of prefix-XOR(j).
  applyRyRz4(ar, ai, &ptab[12]);
  float A = 0.f, B2 = 0.f, B1 = 0.f, B0 = 0.f;
#pragma unroll
  for (int r = 0; r < 16; ++r) {
    float p = ar[r] * ar[r] + ai[r] * ai[r];
    int tr = r ^ (r << 1); tr ^= (tr << 2);  // 4-bit prefix-xor of r
    A  += ((tr >> 3) & 1) ? -p : p;
    B2 += ((tr >> 2) & 1) ? -p : p;
    B1 += ((tr >> 1) & 1) ? -p : p;
    B0 += ((tr & 1)      ) ? -p : p;
  }
  int t03p = __popc(tid & 0x0F) & 1;   // parity t0-3
  int t47p = __popc(tid & 0xF0) & 1;   // parity t4-7
  int u4   = (tid >> 4) & 1;
  int u45  = u4 ^ ((tid >> 5) & 1);
  int u456 = u45 ^ ((tid >> 6) & 1);
  int v0   = tid & 1;
  int v01  = v0 ^ ((tid >> 1) & 1);
  int v012 = v01 ^ ((tid >> 2) & 1);
  float feat[12];
  feat[0]  = (t47p ^ t03p) ? -A : A;
  feat[1]  = (t47p ^ v012) ? -A : A;
  feat[2]  = (t47p ^ v01)  ? -A : A;
  feat[3]  = (t47p ^ v0)   ? -A : A;
  feat[4]  = t47p ? -A : A;
  feat[5]  = u456 ? -A : A;
  feat[6]  = u45  ? -A : A;
  feat[7]  = u4   ? -A : A;
  feat[8]  = A;
  feat[9]  = B2;
  feat[10] = B1;
  feat[11] = B0;

#pragma unroll
  for (int q = 0; q < 12; ++q) feat[q] = waveReduce(feat[q]);
  int wid = tid >> 6;
  if ((tid & 63) == 0) {
#pragma unroll
    for (int q = 0; q < 12; ++q) red[wid][q] = feat[q];
  }
  __syncthreads();
  if (tid < 12) {
    float v = red[0][tid] + red[1][tid] + red[2][tid] + red[3][tid];
    float* dst;
    if (which == 1)      dst = featBase + (((h << 3) + b) * 64 + t) * 12;
    else if (which == 2) dst = featBase + 12288 + (((h << 3) + b) * 64 + t) * 12;
    else                 dst = featBase + 24576 + ((h << 3) + b) * 12;
    dst[tid] = v;
  }
}

// ================= MONOLITHIC FALLBACK =================

__global__ __launch_bounds__(256, 2) void qstates_mono(
    const float* __restrict__ seq, const float* __restrict__ resp,
    const float* __restrict__ hparams, float* __restrict__ featBase) {
  __shared__ float sRe[PADDED], sIm[PADDED];
  __shared__ float4 qtab[12];
  __shared__ float utab[36][8];
  __shared__ float4 ptab[24];
  __shared__ float red[4][12];

  const int tid = threadIdx.x;
  const int blk = blockIdx.x;
  const int b = blk >> 6;
  const int t = blk & 63;
  const float x = seq[blk];

  buildQtab(qtab, tid, x);
  buildUtab(utab, tid, resp);
  __syncthreads();
  initProduct(sRe, sIm, tid, qtab);
  __syncthreads();

  for (int l = 0; l < 3; ++l) {
    int czm = (l & 1) ? 0x2AA : 0x555;
    encPass<0>(sRe, sIm, tid, (l == 0) ? 1 : 2, &utab[l * 12], 0);
    encPass<1>(sRe, sIm, tid, 0, &utab[l * 12 + 4], 0);
    encPass<2>(sRe, sIm, tid, 0, &utab[l * 12 + 8], czm);
  }

  float encR[16], encI[16];
#pragma unroll
  for (int r = 0; r < 16; ++r) {
    int j = (tid << 4) | r;
    int a = PD(j ^ ((j & 1) << 11));
    encR[r] = sRe[a]; encI[r] = sIm[a];
  }

  const int nproj = (t == 63) ? 6 : 4;
  for (int pj = 0; pj < nproj; ++pj) {
    int h, which;
    if (pj < 4) { h = pj >> 1; which = (pj & 1) ? 2 : 1; }
    else        { h = pj - 4;  which = 0; }
    buildPtab(ptab, tid, hparams + (h * 3 + which) * 48);
    __syncthreads();

    float ar[16], ai[16];
#pragma unroll
    for (int r = 0; r < 16; ++r) { ar[r] = encR[r]; ai[r] = encI[r]; }
    applyRyRz4(ar, ai, &ptab[0]);
    ldsWrite16<0>(sRe, sIm, tid, ar, ai, 0);
    __syncthreads();
    projPass<1>(sRe, sIm, tid, 0, &ptab[4]);
    projPass<2>(sRe, sIm, tid, 0, &ptab[8]);
    projPass<0>(sRe, sIm, tid, 3, &ptab[12]);
    projPass<1>(sRe, sIm, tid, 0, &ptab[16]);

    float feat[12];
    projFinal(sRe, sIm, tid, &ptab[20], feat);
#pragma unroll
    for (int q = 0; q < 12; ++q) feat[q] = waveReduce(feat[q]);
    int wid = tid >> 6;
    if ((tid & 63) == 0) {
#pragma unroll
      for (int q = 0; q < 12; ++q) red[wid][q] = feat[q];
    }
    __syncthreads();
    if (tid < 12) {
      float v = red[0][tid] + red[1][tid] + red[2][tid] + red[3][tid];
      float* dst;
      if (which == 1)      dst = featBase + (((h << 3) + b) * 64 + t) * 12;
      else if (which == 2) dst = featBase + 12288 + (((h << 3) + b) * 64 + t) * 12;
      else                 dst = featBase + 24576 + ((h << 3) + b) * 12;
      dst[tid] = v;
    }
    __syncthreads();
  }
}

// ================= HEAD =================

__global__ __launch_bounds__(64) void qhead_kernel(
    const float* __restrict__ featBase,
    const float* __restrict__ W1, const float* __restrict__ b1,
    const float* __restrict__ W2, const float* __restrict__ b2,
    float* __restrict__ out) {
  __shared__ float feats[24];
  __shared__ float hdn[48];
  const int b = blockIdx.x;
  const int lane = threadIdx.x;
  const float* Kf = featBase;
  const float* Vf = featBase + 12288;
  const float* Qf = featBase + 24576;
  for (int h = 0; h < 2; ++h) {
    const float* q  = Qf + ((h << 3) + b) * 12;
    const float* kr = Kf + ((((h << 3) + b) << 6) + lane) * 12;
    float dot = 0.f;
#pragma unroll
    for (int d = 0; d < 12; ++d) dot += q[d] * kr[d];
    dot *= 0.288675134594812882f;
    float mx = dot;
#pragma unroll
    for (int off = 32; off; off >>= 1) mx = fmaxf(mx, __shfl_xor(mx, off, 64));
    float e = expf(dot - mx);
    float se = e;
#pragma unroll
    for (int off = 32; off; off >>= 1) se += __shfl_xor(se, off, 64);
    float a = e / se;
    const float* vr = Vf + ((((h << 3) + b) << 6) + lane) * 12;
#pragma unroll
    for (int d = 0; d < 12; ++d) {
      float v = a * vr[d];
#pragma unroll
      for (int off = 32; off; off >>= 1) v += __shfl_xor(v, off, 64);
      if (lane == 0) feats[h * 12 + d] = v;
    }
  }
  __syncthreads();
  if (lane < 48) {
    float acc = b1[lane];
#pragma unroll
    for (int f = 0; f < 24; ++f) acc += feats[f] * W1[f * 48 + lane];
    hdn[lane] = 0.5f * acc * (1.0f + erff(acc * 0.70710678118654752440f));
  }
  __syncthreads();
  if (lane < 4) {
    float acc = b2[lane];
#pragma unroll
    for (int k = 0; k < 48; ++k) acc += hdn[k] * W2[k * 4 + lane];
    out[(b << 2) | lane] = acc;
  }
}

extern "C" void kernel_launch(void* const* d_in, const int* in_sizes, int n_in,
                              void* d_out, int out_size, void* d_ws, size_t ws_size,
                              hipStream_t stream) {
  const float* seq     = (const float*)d_in[0];
  const float* resp    = (const float*)d_in[1];
  const float* hparams = (const float*)d_in[2];
  const float* W1      = (const float*)d_in[3];
  const float* b1      = (const float*)d_in[4];
  const float* W2      = (const float*)d_in[5];
  const float* b2      = (const float*)d_in[6];
  float* out = (float*)d_out;
  float* ws  = (float*)d_ws;

  const size_t needSplit = ((size_t)512 * 8192 + 24768) * sizeof(float);
  if (ws_size >= needSplit) {
    float* wsStates = ws;
    float* featBase = ws + (size_t)512 * 8192;
    hipLaunchKernelGGL(enc_kernel, dim3(512), dim3(256), 0, stream, seq, resp, wsStates);
    hipLaunchKernelGGL(proj_split, dim3(2064), dim3(256), 0, stream, wsStates, hparams, featBase);
    hipLaunchKernelGGL(qhead_kernel, dim3(8), dim3(64), 0, stream, featBase, W1, b1, W2, b2, out);
  } else {
    hipLaunchKernelGGL(qstates_mono, dim3(512), dim3(256), 0, stream, seq, resp, hparams, ws);
    hipLaunchKernelGGL(qhead_kernel, dim3(8), dim3(64), 0, stream, ws, W1, b1, W2, b2, out);
  }
}

// Round 3
// 165.833 us; speedup vs baseline: 1.4233x; 1.0340x over previous
//
#include <hip/hip_runtime.h>
#include <hip/hip_bf16.h>

// 12-qubit statevector pipeline, fp32.
// Split path (ws >= ~17MB):
//   enc_kernel : 512 blocks, encode reservoir state -> ws (CX_LONG folded).
//   proj_split : 2064 blocks, HALF-state LDS (17.5KB).
//                launch_bounds(256,5): VGPR budget ~102.
//                  (256,8) budget 64 -> full spill (VGPR=32, 349MB scratch wr).
//                  (256,6) budget 85 -> one 16-float array still spilled
//                  (VGPR=40, 35.8MB scratch wr = 2064*256*64B). True pressure ~90.
//   qhead_kernel: attention last-row + MLP -> d_out.
// Fallback monolithic path if ws is small.

#define PADDED 4224  // 4096 + 4096/32 padding (full-state buffers: enc + mono)
#define HPAD   2112  // 2048 + 2048/32 padding (half-state buffer: proj_split)

#define LDSFENCE asm volatile("s_waitcnt lgkmcnt(0)" ::: "memory")

__device__ __forceinline__ int PD(int j) { return j + (j >> 5); }
__device__ __forceinline__ int PH(int i) { return i + (i >> 5); }

// mode 0: identity; 1: encode ladder+ring read map; 2: CX_LONG; 3: ladder only
__device__ __forceinline__ int mapIdx(int j, int mode) {
  if (mode == 1) { int k = j ^ ((j >> 11) & 1); return k ^ ((k & 0x7FF) << 1); }
  if (mode == 2) { return j ^ ((j & 1) << 11); }
  if (mode == 3) { return j ^ ((j & 0x7FF) << 1); }
  return j;
}

// L0: bits 0-3 local; L1: bits 4-7 local; L2: bits 8-11 local;
// L3: bits 0-3 local with swapped tid nibbles (j8-11=tid0-3, j4-7=tid4-7)
template <int L>
__device__ __forceinline__ int layoutIdx(int tid, int r) {
  if constexpr (L == 0) return (tid << 4) | r;
  else if constexpr (L == 1) return ((tid & 0xF0) << 4) | (r << 4) | (tid & 15);
  else if constexpr (L == 2) return (r << 8) | tid;
  else return ((tid & 15) << 8) | (tid & 0xF0) | r;
}

// drop bit B of a 12-bit element index -> 11-bit half-buffer index
template <int B>
__device__ __forceinline__ int dropbit(int j) {
  constexpr int lo = (1 << B) - 1;
  return (j & lo) | ((j >> 1) & ~lo);
}

template <int L>
__device__ __forceinline__ void ldsRead16(const float* sR, const float* sI, int tid, int mode,
                                          float ar[16], float ai[16]) {
#pragma unroll
  for (int r = 0; r < 16; ++r) {
    int j = layoutIdx<L>(tid, r);
    int a = PD(mapIdx(j, mode));
    ar[r] = sR[a]; ai[r] = sI[a];
  }
}

template <int L>
__device__ __forceinline__ void ldsWrite16(float* sR, float* sI, int tid,
                                           const float ar[16], const float ai[16], int czmask) {
#pragma unroll
  for (int r = 0; r < 16; ++r) {
    int j = layoutIdx<L>(tid, r);
    float vr = ar[r], vi = ai[r];
    if (czmask) {
      float sg = (__popc((j & (j >> 1)) & czmask) & 1) ? -1.0f : 1.0f;
      vr *= sg; vi *= sg;
    }
    int a = PD(j);
    sR[a] = vr; sI[a] = vi;
  }
}

// half-buffer exchange I/O (proj_split)
template <int L, int B>
__device__ __forceinline__ void hWrite16(float* hR, float* hI, int tid,
                                         const float ar[16], const float ai[16]) {
#pragma unroll
  for (int r = 0; r < 16; ++r) {
    int j = layoutIdx<L>(tid, r);
    int a = PH(dropbit<B>(j));
    hR[a] = ar[r]; hI[a] = ai[r];
  }
}

template <int L, int B, int MODE>
__device__ __forceinline__ void hRead16(const float* hR, const float* hI, int tid,
                                        float ar[16], float ai[16]) {
#pragma unroll
  for (int r = 0; r < 16; ++r) {
    int j = mapIdx(layoutIdx<L>(tid, r), MODE);
    int a = PH(dropbit<B>(j));
    ar[r] = hR[a]; ai[r] = hI[a];
  }
}

// 4 U3 gates on local bits 0..3; u00 is real (= cos t/2), exploit u[1]==0.
__device__ __forceinline__ void applyU34(float ar[16], float ai[16], const float (*ut)[8]) {
#pragma unroll
  for (int b = 0; b < 4; ++b) {
    const float* u = ut[b];
    float u00r = u[0];
    float u01r = u[2], u01i = u[3];
    float u10r = u[4], u10i = u[5], u11r = u[6], u11i = u[7];
#pragma unroll
    for (int m = 0; m < 8; ++m) {
      int p0 = ((m >> b) << (b + 1)) | (m & ((1 << b) - 1));
      int p1 = p0 | (1 << b);
      float x0r = ar[p0], x0i = ai[p0], x1r = ar[p1], x1i = ai[p1];
      ar[p0] = u00r * x0r + u01r * x1r - u01i * x1i;
      ai[p0] = u00r * x0i + u01r * x1i + u01i * x1r;
      ar[p1] = u10r * x0r - u10i * x0i + u11r * x1r - u11i * x1i;
      ai[p1] = u10r * x0i + u10i * x0r + u11r * x1i + u11i * x1r;
    }
  }
}

// 4 fused RY+RZ gates, global phase dropped: G = diag(1, e^{i phi}) * RY(theta)
__device__ __forceinline__ void applyRyRz4(float ar[16], float ai[16], const float4* gt) {
#pragma unroll
  for (int b = 0; b < 4; ++b) {
    float4 g = gt[b];
    float c = g.x, s = g.y, zr = g.z, zi = g.w;
#pragma unroll
    for (int m = 0; m < 8; ++m) {
      int p0 = ((m >> b) << (b + 1)) | (m & ((1 << b) - 1));
      int p1 = p0 | (1 << b);
      float x0r = ar[p0], x0i = ai[p0], x1r = ar[p1], x1i = ai[p1];
      float n0r = c * x0r - s * x1r;
      float n0i = c * x0i - s * x1i;
      float wr  = s * x0r + c * x1r;
      float wi  = s * x0i + c * x1i;
      ar[p0] = n0r;              ai[p0] = n0i;
      ar[p1] = wr * zr - wi * zi; ai[p1] = wr * zi + wi * zr;
    }
  }
}

template <int L>
__device__ __forceinline__ void encPass(float* sR, float* sI, int tid, int mode,
                                        const float (*ut)[8], int czmask) {
  float ar[16], ai[16];
  ldsRead16<L>(sR, sI, tid, mode, ar, ai);
  if (mode != 0) __syncthreads();
  applyU34(ar, ai, ut);
  ldsWrite16<L>(sR, sI, tid, ar, ai, czmask);
  __syncthreads();
}

template <int L>
__device__ __forceinline__ void projPass(float* sR, float* sI, int tid, int mode, const float4* gt) {
  float ar[16], ai[16];
  ldsRead16<L>(sR, sI, tid, mode, ar, ai);
  if (mode != 0) __syncthreads();
  applyRyRz4(ar, ai, gt);
  ldsWrite16<L>(sR, sI, tid, ar, ai, 0);
  __syncthreads();
}

// Final projection pass (mono path, L2 layout)
__device__ __forceinline__ void projFinal(const float* sR, const float* sI, int tid,
                                          const float4* gt, float feat[12]) {
  float ar[16], ai[16];
#pragma unroll
  for (int r = 0; r < 16; ++r) {
    int a = PD((r << 8) | tid);
    ar[r] = sR[a]; ai[r] = sI[a];
  }
  applyRyRz4(ar, ai, gt);
  float sp = 0.f, f0 = 0.f, f1 = 0.f, f2 = 0.f, f3 = 0.f;
  int pt = __popc(tid) & 1;
#pragma unroll
  for (int r = 0; r < 16; ++r) {
    float p = ar[r] * ar[r] + ai[r] * ai[r];
    sp += p;
    int tr = r ^ (r << 1); tr ^= (tr << 2);
    f0 += ((pt ^ ((tr >> 3) & 1)) ? -p : p);
    f1 += ((pt ^ ((tr >> 2) & 1)) ? -p : p);
    f2 += ((pt ^ ((tr >> 1) & 1)) ? -p : p);
    f3 += ((pt ^ (tr & 1)) ? -p : p);
  }
  feat[0] = f0; feat[1] = f1; feat[2] = f2; feat[3] = f3;
  int tt = tid ^ (tid << 1); tt ^= (tt << 2); tt ^= (tt << 4);
#pragma unroll
  for (int q = 4; q < 12; ++q)
    feat[q] = ((tt >> (11 - q)) & 1) ? -sp : sp;
}

__device__ __forceinline__ float waveReduce(float v) {
#pragma unroll
  for (int off = 32; off; off >>= 1) v += __shfl_xor(v, off, 64);
  return v;
}

// ---- shared setup helpers ----

__device__ __forceinline__ void buildQtab(float4* qtab, int tid, float x) {
  const float PI = 3.14159265358979323846f;
  const float RS2 = 0.70710678118654752440f;
  if (tid < 12) {
    int i = tid;
    float th = x * PI * (float)(i + 1) / 12.0f;
    float ph = x * PI / (float)(i + 1);
    float s, c;  sincosf(0.5f * th, &s, &c);
    float zi, zr; sincosf(0.5f * ph, &zi, &zr);
    float k0 = (c - s) * RS2, k1 = (c + s) * RS2;
    qtab[i] = make_float4(k0 * zr, -k0 * zi, k1 * zr, k1 * zi);
  }
}

__device__ __forceinline__ void buildUtab(float (*utab)[8], int tid, const float* resp) {
  if (tid >= 64 && tid < 100) {
    int i = tid - 64;
    const float* rp = resp + i * 3;
    float st, ct;  sincosf(0.5f * rp[0], &st, &ct);
    float sp2, cp; sincosf(rp[1], &sp2, &cp);
    float sl, cl;  sincosf(rp[2], &sl, &cl);
    float spl, cpl; sincosf(rp[1] + rp[2], &spl, &cpl);
    float* u = utab[i];
    u[0] = ct;       u[1] = 0.0f;
    u[2] = -cl * st; u[3] = -sl * st;
    u[4] = cp * st;  u[5] = sp2 * st;
    u[6] = cpl * ct; u[7] = spl * ct;
  }
}

__device__ __forceinline__ void initProduct(float* sRe, float* sIm, int tid, const float4* qtab) {
  float pr, pi;
  {
    float4 g = qtab[4];
    int sb = tid & 1;
    pr = sb ? g.z : g.x; pi = sb ? g.w : g.y;
  }
#pragma unroll
  for (int q = 5; q < 12; ++q) {
    float4 g = qtab[q];
    int sb = (tid >> (q - 4)) & 1;
    float fr = sb ? g.z : g.x, fi = sb ? g.w : g.y;
    float nr = pr * fr - pi * fi;
    pi = pr * fi + pi * fr; pr = nr;
  }
  float4 g0 = qtab[0], g1 = qtab[1], g2 = qtab[2], g3 = qtab[3];
  float c01r[4], c01i[4], c23r[4], c23i[4];
#pragma unroll
  for (int i2 = 0; i2 < 4; ++i2) {
    float f0r = (i2 & 1) ? g0.z : g0.x, f0i = (i2 & 1) ? g0.w : g0.y;
    float f1r = (i2 & 2) ? g1.z : g1.x, f1i = (i2 & 2) ? g1.w : g1.y;
    c01r[i2] = f0r * f1r - f0i * f1i; c01i[i2] = f0r * f1i + f0i * f1r;
    float f2r = (i2 & 1) ? g2.z : g2.x, f2i = (i2 & 1) ? g2.w : g2.y;
    float f3r = (i2 & 2) ? g3.z : g3.x, f3i = (i2 & 2) ? g3.w : g3.y;
    c23r[i2] = f2r * f3r - f2i * f3i; c23i[i2] = f2r * f3i + f2i * f3r;
  }
#pragma unroll
  for (int r = 0; r < 16; ++r) {
    float lr = c01r[r & 3] * c23r[r >> 2] - c01i[r & 3] * c23i[r >> 2];
    float li = c01r[r & 3] * c23i[r >> 2] + c01i[r & 3] * c23r[r >> 2];
    int a = PD((tid << 4) | r);
    sRe[a] = pr * lr - pi * li;
    sIm[a] = pr * li + pi * lr;
  }
}

__device__ __forceinline__ void buildPtab(float4* ptab, int tid, const float* hp) {
  if (tid < 24) {
    int k = tid * 2;
    float s, c;  sincosf(0.5f * hp[k], &s, &c);
    float zi, zr; sincosf(hp[k + 1], &zi, &zr);
    ptab[tid] = make_float4(c, s, zr, zi);
  }
}

// ================= SPLIT PATH =================

// Kernel A: encode -> global (grid-limited to 2 blocks/CU; next target).
__global__ __launch_bounds__(256, 2) void enc_kernel(
    const float* __restrict__ seq, const float* __restrict__ resp,
    float* __restrict__ wsStates) {
  __shared__ float sRe[PADDED], sIm[PADDED];
  __shared__ float4 qtab[12];
  __shared__ float utab[36][8];

  const int tid = threadIdx.x;
  const int blk = blockIdx.x;
  const float x = seq[blk];

  buildQtab(qtab, tid, x);
  buildUtab(utab, tid, resp);
  __syncthreads();

  initProduct(sRe, sIm, tid, qtab);
  __syncthreads();

  encPass<0>(sRe, sIm, tid, 1, &utab[0], 0);
  encPass<1>(sRe, sIm, tid, 0, &utab[4], 0);
  encPass<2>(sRe, sIm, tid, 0, &utab[8], 0x555);
  encPass<0>(sRe, sIm, tid, 2, &utab[12], 0);
  encPass<1>(sRe, sIm, tid, 0, &utab[16], 0);
  encPass<2>(sRe, sIm, tid, 0, &utab[20], 0x2AA);
  encPass<0>(sRe, sIm, tid, 2, &utab[24], 0);
  encPass<1>(sRe, sIm, tid, 0, &utab[28], 0);

  {
    float ar[16], ai[16];
    ldsRead16<2>(sRe, sIm, tid, 0, ar, ai);
    applyU34(ar, ai, &utab[32]);
    float* gR = wsStates + (size_t)blk * 8192;
    float* gI = gR + 4096;
#pragma unroll
    for (int r = 0; r < 16; ++r) {
      int j = (r << 8) | tid;
      float sg = (__popc((j & (j >> 1)) & 0x555) & 1) ? -1.0f : 1.0f;
      int g = j ^ ((j & 1) << 11);
      gR[g] = sg * ar[r];
      gI[g] = sg * ai[r];
    }
  }
}

// Kernel B: one projection per block, HALF-state LDS buffer.
//
// Each exchange between layouts moves the full 4096-element state through a
// 2048-entry buffer in two phases, split by an element-index bit B that is a
// per-thread-constant on BOTH the write side and the read side:
//   E1: L0->L1           B=11 (tid7/tid7)  intra-wave per phase (fence only)
//   E2: L1->L2           B=3  (tid3/tid3)
//   E3: L2->L1+ladder    B=0  (tid0/tid0)  (ladder map preserves bit 0)
//   E4: L1->L2           B=3
//   E5: L2->L3           B=7  (tid7/tid7)  intra-wave per phase
// Layer-1 gate order is q4-7, q8-11, q0-3 (commuting) to make E3 phase-matched.
//
// launch_bounds(256,5): VGPR budget ~102. History: (256,8)=64 -> full spill;
// (256,6)=85 -> one array spilled (VGPR=40, 35.8MB scratch). Pressure ~90.
__global__ __launch_bounds__(256, 5) void proj_split(
    const float* __restrict__ wsStates, const float* __restrict__ hparams,
    float* __restrict__ featBase) {
  __shared__ float hRe[HPAD], hIm[HPAD];
  __shared__ float4 ptab[24];
  __shared__ float red[4][12];

  const int tid = threadIdx.x;
  const int bid = blockIdx.x;
  int h, which, s;
  if (bid < 2048) { s = bid >> 2; int pp = bid & 3; h = pp >> 1; which = 1 + (pp & 1); }
  else            { int i = bid - 2048; h = i & 1; s = (((i >> 1) << 6) | 63); which = 0; }
  const int b = s >> 6, t = s & 63;

  buildPtab(ptab, tid, hparams + (h * 3 + which) * 48);

  // coalesced load of the encoded state: thread owns j = 16*tid .. 16*tid+15 (L0)
  float ar[16], ai[16];
  const float4* pR = (const float4*)(wsStates + (size_t)s * 8192 + (tid << 4));
  const float4* pI = (const float4*)(wsStates + (size_t)s * 8192 + 4096 + (tid << 4));
#pragma unroll
  for (int k = 0; k < 4; ++k) {
    float4 vr = pR[k], vi = pI[k];
    ar[4 * k] = vr.x; ar[4 * k + 1] = vr.y; ar[4 * k + 2] = vr.z; ar[4 * k + 3] = vr.w;
    ai[4 * k] = vi.x; ai[4 * k + 1] = vi.y; ai[4 * k + 2] = vi.z; ai[4 * k + 3] = vi.w;
  }
  __syncthreads();  // ptab ready

  const int ph7 = (tid >> 7) & 1;
  const int ph3 = (tid >> 3) & 1;
  const int ph0 = tid & 1;

  // P0: layer-0 q0-3 on regs (L0)
  applyRyRz4(ar, ai, &ptab[0]);

  // E1: write L0 -> read L1; phase tid7; intra-wave within phase
  if (ph7 == 0) { hWrite16<0, 11>(hRe, hIm, tid, ar, ai); LDSFENCE; hRead16<1, 11, 0>(hRe, hIm, tid, ar, ai); }
  __syncthreads();
  if (ph7 == 1) { hWrite16<0, 11>(hRe, hIm, tid, ar, ai); LDSFENCE; hRead16<1, 11, 0>(hRe, hIm, tid, ar, ai); }

  // P2: layer-0 q4-7 (L1)
  applyRyRz4(ar, ai, &ptab[4]);

  // E2: write L1 -> read L2; phase tid3
  __syncthreads();
  if (ph3 == 0) hWrite16<1, 3>(hRe, hIm, tid, ar, ai);
  __syncthreads();
  if (ph3 == 0) hRead16<2, 3, 0>(hRe, hIm, tid, ar, ai);
  __syncthreads();
  if (ph3 == 1) hWrite16<1, 3>(hRe, hIm, tid, ar, ai);
  __syncthreads();
  if (ph3 == 1) hRead16<2, 3, 0>(hRe, hIm, tid, ar, ai);

  // P3: layer-0 q8-11 (L2)
  applyRyRz4(ar, ai, &ptab[8]);

  // E3: write L2 -> read L1 with ladder fold (mode 3); phase tid0
  __syncthreads();
  if (ph0 == 0) hWrite16<2, 0>(hRe, hIm, tid, ar, ai);
  __syncthreads();
  if (ph0 == 0) hRead16<1, 0, 3>(hRe, hIm, tid, ar, ai);
  __syncthreads();
  if (ph0 == 1) hWrite16<2, 0>(hRe, hIm, tid, ar, ai);
  __syncthreads();
  if (ph0 == 1) hRead16<1, 0, 3>(hRe, hIm, tid, ar, ai);

  // P4: layer-1 q4-7 (L1)
  applyRyRz4(ar, ai, &ptab[16]);

  // E4: write L1 -> read L2; phase tid3
  __syncthreads();
  if (ph3 == 0) hWrite16<1, 3>(hRe, hIm, tid, ar, ai);
  __syncthreads();
  if (ph3 == 0) hRead16<2, 3, 0>(hRe, hIm, tid, ar, ai);
  __syncthreads();
  if (ph3 == 1) hWrite16<1, 3>(hRe, hIm, tid, ar, ai);
  __syncthreads();
  if (ph3 == 1) hRead16<2, 3, 0>(hRe, hIm, tid, ar, ai);

  // P5: layer-1 q8-11 (L2)
  applyRyRz4(ar, ai, &ptab[20]);

  // E5: write L2 -> read L3 (swapped-nibble L0); phase tid7; intra-wave
  __syncthreads();
  if (ph7 == 0) { hWrite16<2, 7>(hRe, hIm, tid, ar, ai); LDSFENCE; hRead16<3, 7, 0>(hRe, hIm, tid, ar, ai); }
  __syncthreads();
  if (ph7 == 1) { hWrite16<2, 7>(hRe, hIm, tid, ar, ai); LDSFENCE; hRead16<3, 7, 0>(hRe, hIm, tid, ar, ai); }

  // P6: layer-1 q0-3 (L3) + measurement with trailing-ladder fold.
  // Element j: j0-3=r, j4-7=tid4-7, j8-11=tid0-3. Sign for qubit q = bit (11-q)
  // of prefix-XOR(j).
  applyRyRz4(ar, ai, &ptab[12]);
  float A = 0.f, B2 = 0.f, B1 = 0.f, B0 = 0.f;
#pragma unroll
  for (int r = 0; r < 16; ++r) {
    float p = ar[r] * ar[r] + ai[r] * ai[r];
    int tr = r ^ (r << 1); tr ^= (tr << 2);  // 4-bit prefix-xor of r
    A  += ((tr >> 3) & 1) ? -p : p;
    B2 += ((tr >> 2) & 1) ? -p : p;
    B1 += ((tr >> 1) & 1) ? -p : p;
    B0 += ((tr & 1)      ) ? -p : p;
  }
  int t03p = __popc(tid & 0x0F) & 1;   // parity t0-3
  int t47p = __popc(tid & 0xF0) & 1;   // parity t4-7
  int u4   = (tid >> 4) & 1;
  int u45  = u4 ^ ((tid >> 5) & 1);
  int u456 = u45 ^ ((tid >> 6) & 1);
  int v0   = tid & 1;
  int v01  = v0 ^ ((tid >> 1) & 1);
  int v012 = v01 ^ ((tid >> 2) & 1);
  float feat[12];
  feat[0]  = (t47p ^ t03p) ? -A : A;
  feat[1]  = (t47p ^ v012) ? -A : A;
  feat[2]  = (t47p ^ v01)  ? -A : A;
  feat[3]  = (t47p ^ v0)   ? -A : A;
  feat[4]  = t47p ? -A : A;
  feat[5]  = u456 ? -A : A;
  feat[6]  = u45  ? -A : A;
  feat[7]  = u4   ? -A : A;
  feat[8]  = A;
  feat[9]  = B2;
  feat[10] = B1;
  feat[11] = B0;

#pragma unroll
  for (int q = 0; q < 12; ++q) feat[q] = waveReduce(feat[q]);
  int wid = tid >> 6;
  if ((tid & 63) == 0) {
#pragma unroll
    for (int q = 0; q < 12; ++q) red[wid][q] = feat[q];
  }
  __syncthreads();
  if (tid < 12) {
    float v = red[0][tid] + red[1][tid] + red[2][tid] + red[3][tid];
    float* dst;
    if (which == 1)      dst = featBase + (((h << 3) + b) * 64 + t) * 12;
    else if (which == 2) dst = featBase + 12288 + (((h << 3) + b) * 64 + t) * 12;
    else                 dst = featBase + 24576 + ((h << 3) + b) * 12;
    dst[tid] = v;
  }
}

// ================= MONOLITHIC FALLBACK =================

__global__ __launch_bounds__(256, 2) void qstates_mono(
    const float* __restrict__ seq, const float* __restrict__ resp,
    const float* __restrict__ hparams, float* __restrict__ featBase) {
  __shared__ float sRe[PADDED], sIm[PADDED];
  __shared__ float4 qtab[12];
  __shared__ float utab[36][8];
  __shared__ float4 ptab[24];
  __shared__ float red[4][12];

  const int tid = threadIdx.x;
  const int blk = blockIdx.x;
  const int b = blk >> 6;
  const int t = blk & 63;
  const float x = seq[blk];

  buildQtab(qtab, tid, x);
  buildUtab(utab, tid, resp);
  __syncthreads();
  initProduct(sRe, sIm, tid, qtab);
  __syncthreads();

  for (int l = 0; l < 3; ++l) {
    int czm = (l & 1) ? 0x2AA : 0x555;
    encPass<0>(sRe, sIm, tid, (l == 0) ? 1 : 2, &utab[l * 12], 0);
    encPass<1>(sRe, sIm, tid, 0, &utab[l * 12 + 4], 0);
    encPass<2>(sRe, sIm, tid, 0, &utab[l * 12 + 8], czm);
  }

  float encR[16], encI[16];
#pragma unroll
  for (int r = 0; r < 16; ++r) {
    int j = (tid << 4) | r;
    int a = PD(j ^ ((j & 1) << 11));
    encR[r] = sRe[a]; encI[r] = sIm[a];
  }

  const int nproj = (t == 63) ? 6 : 4;
  for (int pj = 0; pj < nproj; ++pj) {
    int h, which;
    if (pj < 4) { h = pj >> 1; which = (pj & 1) ? 2 : 1; }
    else        { h = pj - 4;  which = 0; }
    buildPtab(ptab, tid, hparams + (h * 3 + which) * 48);
    __syncthreads();

    float ar[16], ai[16];
#pragma unroll
    for (int r = 0; r < 16; ++r) { ar[r] = encR[r]; ai[r] = encI[r]; }
    applyRyRz4(ar, ai, &ptab[0]);
    ldsWrite16<0>(sRe, sIm, tid, ar, ai, 0);
    __syncthreads();
    projPass<1>(sRe, sIm, tid, 0, &ptab[4]);
    projPass<2>(sRe, sIm, tid, 0, &ptab[8]);
    projPass<0>(sRe, sIm, tid, 3, &ptab[12]);
    projPass<1>(sRe, sIm, tid, 0, &ptab[16]);

    float feat[12];
    projFinal(sRe, sIm, tid, &ptab[20], feat);
#pragma unroll
    for (int q = 0; q < 12; ++q) feat[q] = waveReduce(feat[q]);
    int wid = tid >> 6;
    if ((tid & 63) == 0) {
#pragma unroll
      for (int q = 0; q < 12; ++q) red[wid][q] = feat[q];
    }
    __syncthreads();
    if (tid < 12) {
      float v = red[0][tid] + red[1][tid] + red[2][tid] + red[3][tid];
      float* dst;
      if (which == 1)      dst = featBase + (((h << 3) + b) * 64 + t) * 12;
      else if (which == 2) dst = featBase + 12288 + (((h << 3) + b) * 64 + t) * 12;
      else                 dst = featBase + 24576 + ((h << 3) + b) * 12;
      dst[tid] = v;
    }
    __syncthreads();
  }
}

// ================= HEAD =================

__global__ __launch_bounds__(64) void qhead_kernel(
    const float* __restrict__ featBase,
    const float* __restrict__ W1, const float* __restrict__ b1,
    const float* __restrict__ W2, const float* __restrict__ b2,
    float* __restrict__ out) {
  __shared__ float feats[24];
  __shared__ float hdn[48];
  const int b = blockIdx.x;
  const int lane = threadIdx.x;
  const float* Kf = featBase;
  const float* Vf = featBase + 12288;
  const float* Qf = featBase + 24576;
  for (int h = 0; h < 2; ++h) {
    const float* q  = Qf + ((h << 3) + b) * 12;
    const float* kr = Kf + ((((h << 3) + b) << 6) + lane) * 12;
    float dot = 0.f;
#pragma unroll
    for (int d = 0; d < 12; ++d) dot += q[d] * kr[d];
    dot *= 0.288675134594812882f;
    float mx = dot;
#pragma unroll
    for (int off = 32; off; off >>= 1) mx = fmaxf(mx, __shfl_xor(mx, off, 64));
    float e = expf(dot - mx);
    float se = e;
#pragma unroll
    for (int off = 32; off; off >>= 1) se += __shfl_xor(se, off, 64);
    float a = e / se;
    const float* vr = Vf + ((((h << 3) + b) << 6) + lane) * 12;
#pragma unroll
    for (int d = 0; d < 12; ++d) {
      float v = a * vr[d];
#pragma unroll
      for (int off = 32; off; off >>= 1) v += __shfl_xor(v, off, 64);
      if (lane == 0) feats[h * 12 + d] = v;
    }
  }
  __syncthreads();
  if (lane < 48) {
    float acc = b1[lane];
#pragma unroll
    for (int f = 0; f < 24; ++f) acc += feats[f] * W1[f * 48 + lane];
    hdn[lane] = 0.5f * acc * (1.0f + erff(acc * 0.70710678118654752440f));
  }
  __syncthreads();
  if (lane < 4) {
    float acc = b2[lane];
#pragma unroll
    for (int k = 0; k < 48; ++k) acc += hdn[k] * W2[k * 4 + lane];
    out[(b << 2) | lane] = acc;
  }
}

extern "C" void kernel_launch(void* const* d_in, const int* in_sizes, int n_in,
                              void* d_out, int out_size, void* d_ws, size_t ws_size,
                              hipStream_t stream) {
  const float* seq     = (const float*)d_in[0];
  const float* resp    = (const float*)d_in[1];
  const float* hparams = (const float*)d_in[2];
  const float* W1      = (const float*)d_in[3];
  const float* b1      = (const float*)d_in[4];
  const float* W2      = (const float*)d_in[5];
  const float* b2      = (const float*)d_in[6];
  float* out = (float*)d_out;
  float* ws  = (float*)d_ws;

  const size_t needSplit = ((size_t)512 * 8192 + 24768) * sizeof(float);
  if (ws_size >= needSplit) {
    float* wsStates = ws;
    float* featBase = ws + (size_t)512 * 8192;
    hipLaunchKernelGGL(enc_kernel, dim3(512), dim3(256), 0, stream, seq, resp, wsStates);
    hipLaunchKernelGGL(proj_split, dim3(2064), dim3(256), 0, stream, wsStates, hparams, featBase);
    hipLaunchKernelGGL(qhead_kernel, dim3(8), dim3(64), 0, stream, featBase, W1, b1, W2, b2, out);
  } else {
    hipLaunchKernelGGL(qstates_mono, dim3(512), dim3(256), 0, stream, seq, resp, hparams, ws);
    hipLaunchKernelGGL(qhead_kernel, dim3(8), dim3(64), 0, stream, ws, W1, b1, W2, b2, out);
  }
}

// Round 4
// 165.097 us; speedup vs baseline: 1.4296x; 1.0045x over previous
//
#include <hip/hip_runtime.h>
#include <hip/hip_bf16.h>

// 12-qubit statevector pipeline, fp32.
// Split path (ws >= ~17MB):
//   enc_kernel : 512 blocks x 512 threads (8 elem/thread, 3-bit-local passes).
//                Rationale: grid is pinned at 512 states; 256-thread blocks gave
//                2 waves/SIMD (latency-starved, ~72us vs ~9us issue floor).
//                512-thread blocks double resident waves to 4/SIMD.
//   proj_split : 2064 blocks, HALF-state LDS (17.5KB), launch_bounds(256,5).
//                History: (256,8)=full spill; (256,6)=one array spilled; (256,5) clean
//                (VGPR=48, scratch=0). Issue-bound at VALUBusy 72%.
//   qhead_kernel: attention last-row + MLP -> d_out.
// Fallback monolithic path if ws is small.

#define PADDED 4224  // 4096 + 4096/32 padding (full-state buffers: enc + mono)
#define HPAD   2112  // 2048 + 2048/32 padding (half-state buffer: proj_split)

#define LDSFENCE asm volatile("s_waitcnt lgkmcnt(0)" ::: "memory")

__device__ __forceinline__ int PD(int j) { return j + (j >> 5); }
__device__ __forceinline__ int PH(int i) { return i + (i >> 5); }

// mode 0: identity; 1: encode ladder+ring read map; 2: CX_LONG; 3: ladder only
__device__ __forceinline__ int mapIdx(int j, int mode) {
  if (mode == 1) { int k = j ^ ((j >> 11) & 1); return k ^ ((k & 0x7FF) << 1); }
  if (mode == 2) { return j ^ ((j & 1) << 11); }
  if (mode == 3) { return j ^ ((j & 0x7FF) << 1); }
  return j;
}

// ---- 4-bit-local layouts (proj + mono) ----
// L0: bits 0-3 local; L1: bits 4-7 local; L2: bits 8-11 local;
// L3: bits 0-3 local with swapped tid nibbles (j8-11=tid0-3, j4-7=tid4-7)
template <int L>
__device__ __forceinline__ int layoutIdx(int tid, int r) {
  if constexpr (L == 0) return (tid << 4) | r;
  else if constexpr (L == 1) return ((tid & 0xF0) << 4) | (r << 4) | (tid & 15);
  else if constexpr (L == 2) return (r << 8) | tid;
  else return ((tid & 15) << 8) | (tid & 0xF0) | r;
}

// ---- 3-bit-local layouts (enc, 512 threads, 8 elem/thread) ----
// K: local bits 3K..3K+2; tid bits fill the rest in order.
template <int K>
__device__ __forceinline__ int layoutIdx3(int tid, int r) {
  constexpr int S = 3 * K;
  int lo = tid & ((1 << S) - 1);
  int hi = tid >> S;
  return (hi << (S + 3)) | (r << S) | lo;
}

// drop bit B of a 12-bit element index -> 11-bit half-buffer index
template <int B>
__device__ __forceinline__ int dropbit(int j) {
  constexpr int lo = (1 << B) - 1;
  return (j & lo) | ((j >> 1) & ~lo);
}

template <int L>
__device__ __forceinline__ void ldsRead16(const float* sR, const float* sI, int tid, int mode,
                                          float ar[16], float ai[16]) {
#pragma unroll
  for (int r = 0; r < 16; ++r) {
    int j = layoutIdx<L>(tid, r);
    int a = PD(mapIdx(j, mode));
    ar[r] = sR[a]; ai[r] = sI[a];
  }
}

template <int L>
__device__ __forceinline__ void ldsWrite16(float* sR, float* sI, int tid,
                                           const float ar[16], const float ai[16], int czmask) {
#pragma unroll
  for (int r = 0; r < 16; ++r) {
    int j = layoutIdx<L>(tid, r);
    float vr = ar[r], vi = ai[r];
    if (czmask) {
      float sg = (__popc((j & (j >> 1)) & czmask) & 1) ? -1.0f : 1.0f;
      vr *= sg; vi *= sg;
    }
    int a = PD(j);
    sR[a] = vr; sI[a] = vi;
  }
}

// half-buffer exchange I/O (proj_split)
template <int L, int B>
__device__ __forceinline__ void hWrite16(float* hR, float* hI, int tid,
                                         const float ar[16], const float ai[16]) {
#pragma unroll
  for (int r = 0; r < 16; ++r) {
    int j = layoutIdx<L>(tid, r);
    int a = PH(dropbit<B>(j));
    hR[a] = ar[r]; hI[a] = ai[r];
  }
}

template <int L, int B, int MODE>
__device__ __forceinline__ void hRead16(const float* hR, const float* hI, int tid,
                                        float ar[16], float ai[16]) {
#pragma unroll
  for (int r = 0; r < 16; ++r) {
    int j = mapIdx(layoutIdx<L>(tid, r), MODE);
    int a = PH(dropbit<B>(j));
    ar[r] = hR[a]; ai[r] = hI[a];
  }
}

// 4 U3 gates on local bits 0..3; u00 is real (= cos t/2), exploit u[1]==0.
__device__ __forceinline__ void applyU34(float ar[16], float ai[16], const float (*ut)[8]) {
#pragma unroll
  for (int b = 0; b < 4; ++b) {
    const float* u = ut[b];
    float u00r = u[0];
    float u01r = u[2], u01i = u[3];
    float u10r = u[4], u10i = u[5], u11r = u[6], u11i = u[7];
#pragma unroll
    for (int m = 0; m < 8; ++m) {
      int p0 = ((m >> b) << (b + 1)) | (m & ((1 << b) - 1));
      int p1 = p0 | (1 << b);
      float x0r = ar[p0], x0i = ai[p0], x1r = ar[p1], x1i = ai[p1];
      ar[p0] = u00r * x0r + u01r * x1r - u01i * x1i;
      ai[p0] = u00r * x0i + u01r * x1i + u01i * x1r;
      ar[p1] = u10r * x0r - u10i * x0i + u11r * x1r - u11i * x1i;
      ai[p1] = u10r * x0i + u10i * x0r + u11r * x1i + u11i * x1r;
    }
  }
}

// 3 U3 gates on local bits 0..2 (8-element state, enc 512-thread path)
__device__ __forceinline__ void applyU3_3(float ar[8], float ai[8], const float (*ut)[8]) {
#pragma unroll
  for (int b = 0; b < 3; ++b) {
    const float* u = ut[b];
    float u00r = u[0];
    float u01r = u[2], u01i = u[3];
    float u10r = u[4], u10i = u[5], u11r = u[6], u11i = u[7];
#pragma unroll
    for (int m = 0; m < 4; ++m) {
      int p0 = ((m >> b) << (b + 1)) | (m & ((1 << b) - 1));
      int p1 = p0 | (1 << b);
      float x0r = ar[p0], x0i = ai[p0], x1r = ar[p1], x1i = ai[p1];
      ar[p0] = u00r * x0r + u01r * x1r - u01i * x1i;
      ai[p0] = u00r * x0i + u01r * x1i + u01i * x1r;
      ar[p1] = u10r * x0r - u10i * x0i + u11r * x1r - u11i * x1i;
      ai[p1] = u10r * x0i + u10i * x0r + u11r * x1i + u11i * x1r;
    }
  }
}

// 4 fused RY+RZ gates, global phase dropped: G = diag(1, e^{i phi}) * RY(theta)
__device__ __forceinline__ void applyRyRz4(float ar[16], float ai[16], const float4* gt) {
#pragma unroll
  for (int b = 0; b < 4; ++b) {
    float4 g = gt[b];
    float c = g.x, s = g.y, zr = g.z, zi = g.w;
#pragma unroll
    for (int m = 0; m < 8; ++m) {
      int p0 = ((m >> b) << (b + 1)) | (m & ((1 << b) - 1));
      int p1 = p0 | (1 << b);
      float x0r = ar[p0], x0i = ai[p0], x1r = ar[p1], x1i = ai[p1];
      float n0r = c * x0r - s * x1r;
      float n0i = c * x0i - s * x1i;
      float wr  = s * x0r + c * x1r;
      float wi  = s * x0i + c * x1i;
      ar[p0] = n0r;              ai[p0] = n0i;
      ar[p1] = wr * zr - wi * zi; ai[p1] = wr * zi + wi * zr;
    }
  }
}

template <int L>
__device__ __forceinline__ void encPass(float* sR, float* sI, int tid, int mode,
                                        const float (*ut)[8], int czmask) {
  float ar[16], ai[16];
  ldsRead16<L>(sR, sI, tid, mode, ar, ai);
  if (mode != 0) __syncthreads();
  applyU34(ar, ai, ut);
  ldsWrite16<L>(sR, sI, tid, ar, ai, czmask);
  __syncthreads();
}

// enc 512-thread pass: read own 8-elem L{K} set (mode-mapped), gates, write back.
template <int K>
__device__ __forceinline__ void encPass3(float* sR, float* sI, int tid, int mode,
                                         const float (*ut)[8], int czmask) {
  float ar[8], ai[8];
#pragma unroll
  for (int r = 0; r < 8; ++r) {
    int j = layoutIdx3<K>(tid, r);
    int a = PD(mapIdx(j, mode));
    ar[r] = sR[a]; ai[r] = sI[a];
  }
  if (mode != 0) __syncthreads();  // read set != write set under a perm fold
  applyU3_3(ar, ai, ut);
#pragma unroll
  for (int r = 0; r < 8; ++r) {
    int j = layoutIdx3<K>(tid, r);
    float vr = ar[r], vi = ai[r];
    if (czmask) {
      float sg = (__popc((j & (j >> 1)) & czmask) & 1) ? -1.0f : 1.0f;
      vr *= sg; vi *= sg;
    }
    int a = PD(j);
    sR[a] = vr; sI[a] = vi;
  }
  __syncthreads();
}

// Final projection pass (mono path, L2 layout)
__device__ __forceinline__ void projFinal(const float* sR, const float* sI, int tid,
                                          const float4* gt, float feat[12]) {
  float ar[16], ai[16];
#pragma unroll
  for (int r = 0; r < 16; ++r) {
    int a = PD((r << 8) | tid);
    ar[r] = sR[a]; ai[r] = sI[a];
  }
  applyRyRz4(ar, ai, gt);
  float sp = 0.f, f0 = 0.f, f1 = 0.f, f2 = 0.f, f3 = 0.f;
  int pt = __popc(tid) & 1;
#pragma unroll
  for (int r = 0; r < 16; ++r) {
    float p = ar[r] * ar[r] + ai[r] * ai[r];
    sp += p;
    int tr = r ^ (r << 1); tr ^= (tr << 2);
    f0 += ((pt ^ ((tr >> 3) & 1)) ? -p : p);
    f1 += ((pt ^ ((tr >> 2) & 1)) ? -p : p);
    f2 += ((pt ^ ((tr >> 1) & 1)) ? -p : p);
    f3 += ((pt ^ (tr & 1)) ? -p : p);
  }
  feat[0] = f0; feat[1] = f1; feat[2] = f2; feat[3] = f3;
  int tt = tid ^ (tid << 1); tt ^= (tt << 2); tt ^= (tt << 4);
#pragma unroll
  for (int q = 4; q < 12; ++q)
    feat[q] = ((tt >> (11 - q)) & 1) ? -sp : sp;
}

__device__ __forceinline__ float waveReduce(float v) {
#pragma unroll
  for (int off = 32; off; off >>= 1) v += __shfl_xor(v, off, 64);
  return v;
}

// ---- shared setup helpers ----

__device__ __forceinline__ void buildQtab(float4* qtab, int tid, float x) {
  const float PI = 3.14159265358979323846f;
  const float RS2 = 0.70710678118654752440f;
  if (tid < 12) {
    int i = tid;
    float th = x * PI * (float)(i + 1) / 12.0f;
    float ph = x * PI / (float)(i + 1);
    float s, c;  sincosf(0.5f * th, &s, &c);
    float zi, zr; sincosf(0.5f * ph, &zi, &zr);
    float k0 = (c - s) * RS2, k1 = (c + s) * RS2;
    qtab[i] = make_float4(k0 * zr, -k0 * zi, k1 * zr, k1 * zi);
  }
}

__device__ __forceinline__ void buildUtab(float (*utab)[8], int tid, const float* resp) {
  if (tid >= 64 && tid < 100) {
    int i = tid - 64;
    const float* rp = resp + i * 3;
    float st, ct;  sincosf(0.5f * rp[0], &st, &ct);
    float sp2, cp; sincosf(rp[1], &sp2, &cp);
    float sl, cl;  sincosf(rp[2], &sl, &cl);
    float spl, cpl; sincosf(rp[1] + rp[2], &spl, &cpl);
    float* u = utab[i];
    u[0] = ct;       u[1] = 0.0f;
    u[2] = -cl * st; u[3] = -sl * st;
    u[4] = cp * st;  u[5] = sp2 * st;
    u[6] = cpl * ct; u[7] = spl * ct;
  }
}

// 256-thread product init (mono path): local j0-3, tid -> j4-11
__device__ __forceinline__ void initProduct(float* sRe, float* sIm, int tid, const float4* qtab) {
  float pr, pi;
  {
    float4 g = qtab[4];
    int sb = tid & 1;
    pr = sb ? g.z : g.x; pi = sb ? g.w : g.y;
  }
#pragma unroll
  for (int q = 5; q < 12; ++q) {
    float4 g = qtab[q];
    int sb = (tid >> (q - 4)) & 1;
    float fr = sb ? g.z : g.x, fi = sb ? g.w : g.y;
    float nr = pr * fr - pi * fi;
    pi = pr * fi + pi * fr; pr = nr;
  }
  float4 g0 = qtab[0], g1 = qtab[1], g2 = qtab[2], g3 = qtab[3];
  float c01r[4], c01i[4], c23r[4], c23i[4];
#pragma unroll
  for (int i2 = 0; i2 < 4; ++i2) {
    float f0r = (i2 & 1) ? g0.z : g0.x, f0i = (i2 & 1) ? g0.w : g0.y;
    float f1r = (i2 & 2) ? g1.z : g1.x, f1i = (i2 & 2) ? g1.w : g1.y;
    c01r[i2] = f0r * f1r - f0i * f1i; c01i[i2] = f0r * f1i + f0i * f1r;
    float f2r = (i2 & 1) ? g2.z : g2.x, f2i = (i2 & 1) ? g2.w : g2.y;
    float f3r = (i2 & 2) ? g3.z : g3.x, f3i = (i2 & 2) ? g3.w : g3.y;
    c23r[i2] = f2r * f3r - f2i * f3i; c23i[i2] = f2r * f3i + f2i * f3r;
  }
#pragma unroll
  for (int r = 0; r < 16; ++r) {
    float lr = c01r[r & 3] * c23r[r >> 2] - c01i[r & 3] * c23i[r >> 2];
    float li = c01r[r & 3] * c23i[r >> 2] + c01i[r & 3] * c23r[r >> 2];
    int a = PD((tid << 4) | r);
    sRe[a] = pr * lr - pi * li;
    sIm[a] = pr * li + pi * lr;
  }
}

// 512-thread product init (enc path): local j0-2 (qubits 0-2), tid bits 0-8 -> j3-11
__device__ __forceinline__ void initProduct3(float* sRe, float* sIm, int tid, const float4* qtab) {
  float pr, pi;
  {
    float4 g = qtab[3];
    int sb = tid & 1;
    pr = sb ? g.z : g.x; pi = sb ? g.w : g.y;
  }
#pragma unroll
  for (int q = 4; q < 12; ++q) {
    float4 g = qtab[q];
    int sb = (tid >> (q - 3)) & 1;
    float fr = sb ? g.z : g.x, fi = sb ? g.w : g.y;
    float nr = pr * fr - pi * fi;
    pi = pr * fi + pi * fr; pr = nr;
  }
  float4 g0 = qtab[0], g1 = qtab[1], g2 = qtab[2];
  float c01r[4], c01i[4];
#pragma unroll
  for (int i2 = 0; i2 < 4; ++i2) {
    float f0r = (i2 & 1) ? g0.z : g0.x, f0i = (i2 & 1) ? g0.w : g0.y;
    float f1r = (i2 & 2) ? g1.z : g1.x, f1i = (i2 & 2) ? g1.w : g1.y;
    c01r[i2] = f0r * f1r - f0i * f1i; c01i[i2] = f0r * f1i + f0i * f1r;
  }
#pragma unroll
  for (int r = 0; r < 8; ++r) {
    float f2r = (r & 4) ? g2.z : g2.x, f2i = (r & 4) ? g2.w : g2.y;
    float lr = c01r[r & 3] * f2r - c01i[r & 3] * f2i;
    float li = c01r[r & 3] * f2i + c01i[r & 3] * f2r;
    int a = PD((tid << 3) | r);
    sRe[a] = pr * lr - pi * li;
    sIm[a] = pr * li + pi * lr;
  }
}

__device__ __forceinline__ void buildPtab(float4* ptab, int tid, const float* hp) {
  if (tid < 24) {
    int k = tid * 2;
    float s, c;  sincosf(0.5f * hp[k], &s, &c);
    float zi, zr; sincosf(hp[k + 1], &zi, &zr);
    ptab[tid] = make_float4(c, s, zr, zi);
  }
}

// ================= SPLIT PATH =================

// Kernel A: encode -> global. 512 threads/block, 8 elem/thread, 3-bit locals.
// Grid is pinned at 512 states -> 2 blocks/CU; 512 threads doubles waves/SIMD
// to 4 vs the 256-thread version's 2 (which was latency-starved).
__global__ __launch_bounds__(512, 4) void enc_kernel(
    const float* __restrict__ seq, const float* __restrict__ resp,
    float* __restrict__ wsStates) {
  __shared__ float sRe[PADDED], sIm[PADDED];
  __shared__ float4 qtab[12];
  __shared__ float utab[36][8];

  const int tid = threadIdx.x;
  const int blk = blockIdx.x;
  const float x = seq[blk];

  buildQtab(qtab, tid, x);
  buildUtab(utab, tid, resp);
  __syncthreads();

  initProduct3(sRe, sIm, tid, qtab);
  __syncthreads();

  // layer 0: q0-2 (ladder+ring fold on read), q3-5, q6-8, q9-11 + CZ(0x555)
  encPass3<0>(sRe, sIm, tid, 1, &utab[0], 0);
  encPass3<1>(sRe, sIm, tid, 0, &utab[3], 0);
  encPass3<2>(sRe, sIm, tid, 0, &utab[6], 0);
  encPass3<3>(sRe, sIm, tid, 0, &utab[9], 0x555);
  // layer 1: CX_LONG fold on first read; CZ(0x2AA)
  encPass3<0>(sRe, sIm, tid, 2, &utab[12], 0);
  encPass3<1>(sRe, sIm, tid, 0, &utab[15], 0);
  encPass3<2>(sRe, sIm, tid, 0, &utab[18], 0);
  encPass3<3>(sRe, sIm, tid, 0, &utab[21], 0x2AA);
  // layer 2: CX_LONG fold on first read
  encPass3<0>(sRe, sIm, tid, 2, &utab[24], 0);
  encPass3<1>(sRe, sIm, tid, 0, &utab[27], 0);
  encPass3<2>(sRe, sIm, tid, 0, &utab[30], 0);

  // final: q9-11 (layer 2), CZ(0x555) + CX_LONG folded into store index
  {
    float ar[8], ai[8];
#pragma unroll
    for (int r = 0; r < 8; ++r) {
      int a = PD((r << 9) | tid);
      ar[r] = sRe[a]; ai[r] = sIm[a];
    }
    applyU3_3(ar, ai, &utab[33]);
    float* gR = wsStates + (size_t)blk * 8192;
    float* gI = gR + 4096;
#pragma unroll
    for (int r = 0; r < 8; ++r) {
      int j = (r << 9) | tid;
      float sg = (__popc((j & (j >> 1)) & 0x555) & 1) ? -1.0f : 1.0f;
      int g = j ^ ((j & 1) << 11);  // involution
      gR[g] = sg * ar[r];
      gI[g] = sg * ai[r];
    }
  }
}

// Kernel B: one projection per block, HALF-state LDS buffer.
//
// Each exchange between layouts moves the full 4096-element state through a
// 2048-entry buffer in two phases, split by an element-index bit B that is a
// per-thread-constant on BOTH the write side and the read side:
//   E1: L0->L1           B=11 (tid7/tid7)  intra-wave per phase (fence only)
//   E2: L1->L2           B=3  (tid3/tid3)
//   E3: L2->L1+ladder    B=0  (tid0/tid0)  (ladder map preserves bit 0)
//   E4: L1->L2           B=3
//   E5: L2->L3           B=7  (tid7/tid7)  intra-wave per phase
// Layer-1 gate order is q4-7, q8-11, q0-3 (commuting) to make E3 phase-matched.
//
// launch_bounds(256,5): VGPR budget ~102. History: (256,8)=64 -> full spill;
// (256,6)=85 -> one array spilled (VGPR=40, 35.8MB scratch). (256,5): clean, VGPR=48.
__global__ __launch_bounds__(256, 5) void proj_split(
    const float* __restrict__ wsStates, const float* __restrict__ hparams,
    float* __restrict__ featBase) {
  __shared__ float hRe[HPAD], hIm[HPAD];
  __shared__ float4 ptab[24];
  __shared__ float red[4][12];

  const int tid = threadIdx.x;
  const int bid = blockIdx.x;
  int h, which, s;
  if (bid < 2048) { s = bid >> 2; int pp = bid & 3; h = pp >> 1; which = 1 + (pp & 1); }
  else            { int i = bid - 2048; h = i & 1; s = (((i >> 1) << 6) | 63); which = 0; }
  const int b = s >> 6, t = s & 63;

  buildPtab(ptab, tid, hparams + (h * 3 + which) * 48);

  // coalesced load of the encoded state: thread owns j = 16*tid .. 16*tid+15 (L0)
  float ar[16], ai[16];
  const float4* pR = (const float4*)(wsStates + (size_t)s * 8192 + (tid << 4));
  const float4* pI = (const float4*)(wsStates + (size_t)s * 8192 + 4096 + (tid << 4));
#pragma unroll
  for (int k = 0; k < 4; ++k) {
    float4 vr = pR[k], vi = pI[k];
    ar[4 * k] = vr.x; ar[4 * k + 1] = vr.y; ar[4 * k + 2] = vr.z; ar[4 * k + 3] = vr.w;
    ai[4 * k] = vi.x; ai[4 * k + 1] = vi.y; ai[4 * k + 2] = vi.z; ai[4 * k + 3] = vi.w;
  }
  __syncthreads();  // ptab ready

  const int ph7 = (tid >> 7) & 1;
  const int ph3 = (tid >> 3) & 1;
  const int ph0 = tid & 1;

  // P0: layer-0 q0-3 on regs (L0)
  applyRyRz4(ar, ai, &ptab[0]);

  // E1: write L0 -> read L1; phase tid7; intra-wave within phase
  if (ph7 == 0) { hWrite16<0, 11>(hRe, hIm, tid, ar, ai); LDSFENCE; hRead16<1, 11, 0>(hRe, hIm, tid, ar, ai); }
  __syncthreads();
  if (ph7 == 1) { hWrite16<0, 11>(hRe, hIm, tid, ar, ai); LDSFENCE; hRead16<1, 11, 0>(hRe, hIm, tid, ar, ai); }

  // P2: layer-0 q4-7 (L1)
  applyRyRz4(ar, ai, &ptab[4]);

  // E2: write L1 -> read L2; phase tid3
  __syncthreads();
  if (ph3 == 0) hWrite16<1, 3>(hRe, hIm, tid, ar, ai);
  __syncthreads();
  if (ph3 == 0) hRead16<2, 3, 0>(hRe, hIm, tid, ar, ai);
  __syncthreads();
  if (ph3 == 1) hWrite16<1, 3>(hRe, hIm, tid, ar, ai);
  __syncthreads();
  if (ph3 == 1) hRead16<2, 3, 0>(hRe, hIm, tid, ar, ai);

  // P3: layer-0 q8-11 (L2)
  applyRyRz4(ar, ai, &ptab[8]);

  // E3: write L2 -> read L1 with ladder fold (mode 3); phase tid0
  __syncthreads();
  if (ph0 == 0) hWrite16<2, 0>(hRe, hIm, tid, ar, ai);
  __syncthreads();
  if (ph0 == 0) hRead16<1, 0, 3>(hRe, hIm, tid, ar, ai);
  __syncthreads();
  if (ph0 == 1) hWrite16<2, 0>(hRe, hIm, tid, ar, ai);
  __syncthreads();
  if (ph0 == 1) hRead16<1, 0, 3>(hRe, hIm, tid, ar, ai);

  // P4: layer-1 q4-7 (L1)
  applyRyRz4(ar, ai, &ptab[16]);

  // E4: write L1 -> read L2; phase tid3
  __syncthreads();
  if (ph3 == 0) hWrite16<1, 3>(hRe, hIm, tid, ar, ai);
  __syncthreads();
  if (ph3 == 0) hRead16<2, 3, 0>(hRe, hIm, tid, ar, ai);
  __syncthreads();
  if (ph3 == 1) hWrite16<1, 3>(hRe, hIm, tid, ar, ai);
  __syncthreads();
  if (ph3 == 1) hRead16<2, 3, 0>(hRe, hIm, tid, ar, ai);

  // P5: layer-1 q8-11 (L2)
  applyRyRz4(ar, ai, &ptab[20]);

  // E5: write L2 -> read L3 (swapped-nibble L0); phase tid7; intra-wave
  __syncthreads();
  if (ph7 == 0) { hWrite16<2, 7>(hRe, hIm, tid, ar, ai); LDSFENCE; hRead16<3, 7, 0>(hRe, hIm, tid, ar, ai); }
  __syncthreads();
  if (ph7 == 1) { hWrite16<2, 7>(hRe, hIm, tid, ar, ai); LDSFENCE; hRead16<3, 7, 0>(hRe, hIm, tid, ar, ai); }

  // P6: layer-1 q0-3 (L3) + measurement with trailing-ladder fold.
  // Element j: j0-3=r, j4-7=tid4-7, j8-11=tid0-3. Sign for qubit q = bit (11-q)
  // of prefix-XOR(j).
  applyRyRz4(ar, ai, &ptab[12]);
  float A = 0.f, B2 = 0.f, B1 = 0.f, B0 = 0.f;
#pragma unroll
  for (int r = 0; r < 16; ++r) {
    float p = ar[r] * ar[r] + ai[r] * ai[r];
    int tr = r ^ (r << 1); tr ^= (tr << 2);  // 4-bit prefix-xor of r
    A  += ((tr >> 3) & 1) ? -p : p;
    B2 += ((tr >> 2) & 1) ? -p : p;
    B1 += ((tr >> 1) & 1) ? -p : p;
    B0 += ((tr & 1)      ) ? -p : p;
  }
  int t03p = __popc(tid & 0x0F) & 1;   // parity t0-3
  int t47p = __popc(tid & 0xF0) & 1;   // parity t4-7
  int u4   = (tid >> 4) & 1;
  int u45  = u4 ^ ((tid >> 5) & 1);
  int u456 = u45 ^ ((tid >> 6) & 1);
  int v0   = tid & 1;
  int v01  = v0 ^ ((tid >> 1) & 1);
  int v012 = v01 ^ ((tid >> 2) & 1);
  float feat[12];
  feat[0]  = (t47p ^ t03p) ? -A : A;
  feat[1]  = (t47p ^ v012) ? -A : A;
  feat[2]  = (t47p ^ v01)  ? -A : A;
  feat[3]  = (t47p ^ v0)   ? -A : A;
  feat[4]  = t47p ? -A : A;
  feat[5]  = u456 ? -A : A;
  feat[6]  = u45  ? -A : A;
  feat[7]  = u4   ? -A : A;
  feat[8]  = A;
  feat[9]  = B2;
  feat[10] = B1;
  feat[11] = B0;

#pragma unroll
  for (int q = 0; q < 12; ++q) feat[q] = waveReduce(feat[q]);
  int wid = tid >> 6;
  if ((tid & 63) == 0) {
#pragma unroll
    for (int q = 0; q < 12; ++q) red[wid][q] = feat[q];
  }
  __syncthreads();
  if (tid < 12) {
    float v = red[0][tid] + red[1][tid] + red[2][tid] + red[3][tid];
    float* dst;
    if (which == 1)      dst = featBase + (((h << 3) + b) * 64 + t) * 12;
    else if (which == 2) dst = featBase + 12288 + (((h << 3) + b) * 64 + t) * 12;
    else                 dst = featBase + 24576 + ((h << 3) + b) * 12;
    dst[tid] = v;
  }
}

// ================= MONOLITHIC FALLBACK =================

__global__ __launch_bounds__(256, 2) void qstates_mono(
    const float* __restrict__ seq, const float* __restrict__ resp,
    const float* __restrict__ hparams, float* __restrict__ featBase) {
  __shared__ float sRe[PADDED], sIm[PADDED];
  __shared__ float4 qtab[12];
  __shared__ float utab[36][8];
  __shared__ float4 ptab[24];
  __shared__ float red[4][12];

  const int tid = threadIdx.x;
  const int blk = blockIdx.x;
  const int b = blk >> 6;
  const int t = blk & 63;
  const float x = seq[blk];

  buildQtab(qtab, tid, x);
  buildUtab(utab, tid, resp);
  __syncthreads();
  initProduct(sRe, sIm, tid, qtab);
  __syncthreads();

  for (int l = 0; l < 3; ++l) {
    int czm = (l & 1) ? 0x2AA : 0x555;
    encPass<0>(sRe, sIm, tid, (l == 0) ? 1 : 2, &utab[l * 12], 0);
    encPass<1>(sRe, sIm, tid, 0, &utab[l * 12 + 4], 0);
    encPass<2>(sRe, sIm, tid, 0, &utab[l * 12 + 8], czm);
  }

  float encR[16], encI[16];
#pragma unroll
  for (int r = 0; r < 16; ++r) {
    int j = (tid << 4) | r;
    int a = PD(j ^ ((j & 1) << 11));
    encR[r] = sRe[a]; encI[r] = sIm[a];
  }

  const int nproj = (t == 63) ? 6 : 4;
  for (int pj = 0; pj < nproj; ++pj) {
    int h, which;
    if (pj < 4) { h = pj >> 1; which = (pj & 1) ? 2 : 1; }
    else        { h = pj - 4;  which = 0; }
    buildPtab(ptab, tid, hparams + (h * 3 + which) * 48);
    __syncthreads();

    float ar[16], ai[16];
#pragma unroll
    for (int r = 0; r < 16; ++r) { ar[r] = encR[r]; ai[r] = encI[r]; }
    applyRyRz4(ar, ai, &ptab[0]);
    ldsWrite16<0>(sRe, sIm, tid, ar, ai, 0);
    __syncthreads();
    {
      float br[16], bi[16];
      ldsRead16<1>(sRe, sIm, tid, 0, br, bi);
      applyRyRz4(br, bi, &ptab[4]);
      ldsWrite16<1>(sRe, sIm, tid, br, bi, 0);
      __syncthreads();
      ldsRead16<2>(sRe, sIm, tid, 0, br, bi);
      applyRyRz4(br, bi, &ptab[8]);
      ldsWrite16<2>(sRe, sIm, tid, br, bi, 0);
      __syncthreads();
      ldsRead16<0>(sRe, sIm, tid, 3, br, bi);
      __syncthreads();
      applyRyRz4(br, bi, &ptab[12]);
      ldsWrite16<0>(sRe, sIm, tid, br, bi, 0);
      __syncthreads();
      ldsRead16<1>(sRe, sIm, tid, 0, br, bi);
      applyRyRz4(br, bi, &ptab[16]);
      ldsWrite16<1>(sRe, sIm, tid, br, bi, 0);
      __syncthreads();
    }

    float feat[12];
    projFinal(sRe, sIm, tid, &ptab[20], feat);
#pragma unroll
    for (int q = 0; q < 12; ++q) feat[q] = waveReduce(feat[q]);
    int wid = tid >> 6;
    if ((tid & 63) == 0) {
#pragma unroll
      for (int q = 0; q < 12; ++q) red[wid][q] = feat[q];
    }
    __syncthreads();
    if (tid < 12) {
      float v = red[0][tid] + red[1][tid] + red[2][tid] + red[3][tid];
      float* dst;
      if (which == 1)      dst = featBase + (((h << 3) + b) * 64 + t) * 12;
      else if (which == 2) dst = featBase + 12288 + (((h << 3) + b) * 64 + t) * 12;
      else                 dst = featBase + 24576 + ((h << 3) + b) * 12;
      dst[tid] = v;
    }
    __syncthreads();
  }
}

// ================= HEAD =================

__global__ __launch_bounds__(64) void qhead_kernel(
    const float* __restrict__ featBase,
    const float* __restrict__ W1, const float* __restrict__ b1,
    const float* __restrict__ W2, const float* __restrict__ b2,
    float* __restrict__ out) {
  __shared__ float feats[24];
  __shared__ float hdn[48];
  const int b = blockIdx.x;
  const int lane = threadIdx.x;
  const float* Kf = featBase;
  const float* Vf = featBase + 12288;
  const float* Qf = featBase + 24576;
  for (int h = 0; h < 2; ++h) {
    const float* q  = Qf + ((h << 3) + b) * 12;
    const float* kr = Kf + ((((h << 3) + b) << 6) + lane) * 12;
    float dot = 0.f;
#pragma unroll
    for (int d = 0; d < 12; ++d) dot += q[d] * kr[d];
    dot *= 0.288675134594812882f;
    float mx = dot;
#pragma unroll
    for (int off = 32; off; off >>= 1) mx = fmaxf(mx, __shfl_xor(mx, off, 64));
    float e = expf(dot - mx);
    float se = e;
#pragma unroll
    for (int off = 32; off; off >>= 1) se += __shfl_xor(se, off, 64);
    float a = e / se;
    const float* vr = Vf + ((((h << 3) + b) << 6) + lane) * 12;
#pragma unroll
    for (int d = 0; d < 12; ++d) {
      float v = a * vr[d];
#pragma unroll
      for (int off = 32; off; off >>= 1) v += __shfl_xor(v, off, 64);
      if (lane == 0) feats[h * 12 + d] = v;
    }
  }
  __syncthreads();
  if (lane < 48) {
    float acc = b1[lane];
#pragma unroll
    for (int f = 0; f < 24; ++f) acc += feats[f] * W1[f * 48 + lane];
    hdn[lane] = 0.5f * acc * (1.0f + erff(acc * 0.70710678118654752440f));
  }
  __syncthreads();
  if (lane < 4) {
    float acc = b2[lane];
#pragma unroll
    for (int k = 0; k < 48; ++k) acc += hdn[k] * W2[k * 4 + lane];
    out[(b << 2) | lane] = acc;
  }
}

extern "C" void kernel_launch(void* const* d_in, const int* in_sizes, int n_in,
                              void* d_out, int out_size, void* d_ws, size_t ws_size,
                              hipStream_t stream) {
  const float* seq     = (const float*)d_in[0];
  const float* resp    = (const float*)d_in[1];
  const float* hparams = (const float*)d_in[2];
  const float* W1      = (const float*)d_in[3];
  const float* b1      = (const float*)d_in[4];
  const float* W2      = (const float*)d_in[5];
  const float* b2      = (const float*)d_in[6];
  float* out = (float*)d_out;
  float* ws  = (float*)d_ws;

  const size_t needSplit = ((size_t)512 * 8192 + 24768) * sizeof(float);
  if (ws_size >= needSplit) {
    float* wsStates = ws;
    float* featBase = ws + (size_t)512 * 8192;
    hipLaunchKernelGGL(enc_kernel, dim3(512), dim3(512), 0, stream, seq, resp, wsStates);
    hipLaunchKernelGGL(proj_split, dim3(2064), dim3(256), 0, stream, wsStates, hparams, featBase);
    hipLaunchKernelGGL(qhead_kernel, dim3(8), dim3(64), 0, stream, featBase, W1, b1, W2, b2, out);
  } else {
    hipLaunchKernelGGL(qstates_mono, dim3(512), dim3(256), 0, stream, seq, resp, hparams, ws);
    hipLaunchKernelGGL(qhead_kernel, dim3(8), dim3(64), 0, stream, ws, W1, b1, W2, b2, out);
  }
}

// Round 5
// 157.569 us; speedup vs baseline: 1.4979x; 1.0478x over previous
//
#include <hip/hip_runtime.h>
#include <hip/hip_bf16.h>

// 12-qubit statevector pipeline, fp32.
// Split path (ws >= ~17MB):
//   enc_kernel : 512 blocks x 512 threads (8 elem/thread, 3-bit-local passes).
//                Grid pinned at 512 states -> 2 blocks/CU; latency-bound.
//                (Round-4 lesson: waves/block don't help; only blocks/CU do.)
//   proj_split : 2064 blocks x 512 threads, FULL-state LDS (34KB), 3-bit-local
//                passes. 4 blocks/CU x 8 waves = 32 waves/CU (100% cap) vs the
//                256-thread version's 3 blocks/12 waves; no phase-masked double
//                issue; 10 barriers vs 14. launch_bounds(512,8) -> VGPR cap 64
//                (state is 16 floats/thread; round-3 fit 32 in 48 VGPRs).
//   qhead_kernel: attention last-row + MLP -> d_out.
// Fallback monolithic path if ws is small.

#define PADDED 4224  // 4096 + 4096/32 padding (full-state buffers)

__device__ __forceinline__ int PD(int j) { return j + (j >> 5); }

// mode 0: identity; 1: encode ladder+ring read map; 2: CX_LONG; 3: ladder only
__device__ __forceinline__ int mapIdx(int j, int mode) {
  if (mode == 1) { int k = j ^ ((j >> 11) & 1); return k ^ ((k & 0x7FF) << 1); }
  if (mode == 2) { return j ^ ((j & 1) << 11); }
  if (mode == 3) { return j ^ ((j & 0x7FF) << 1); }
  return j;
}

// ---- 4-bit-local layouts (mono fallback) ----
template <int L>
__device__ __forceinline__ int layoutIdx(int tid, int r) {
  if constexpr (L == 0) return (tid << 4) | r;
  else if constexpr (L == 1) return ((tid & 0xF0) << 4) | (r << 4) | (tid & 15);
  else return (r << 8) | tid;
}

// ---- 3-bit-local layouts (512 threads, 8 elem/thread) ----
// K: local bits 3K..3K+2 = r; tid bits fill the remaining 9 bits in order.
template <int K>
__device__ __forceinline__ int layoutIdx3(int tid, int r) {
  constexpr int S = 3 * K;
  int lo = tid & ((1 << S) - 1);
  int hi = tid >> S;
  return (hi << (S + 3)) | (r << S) | lo;
}

template <int L>
__device__ __forceinline__ void ldsRead16(const float* sR, const float* sI, int tid, int mode,
                                          float ar[16], float ai[16]) {
#pragma unroll
  for (int r = 0; r < 16; ++r) {
    int j = layoutIdx<L>(tid, r);
    int a = PD(mapIdx(j, mode));
    ar[r] = sR[a]; ai[r] = sI[a];
  }
}

template <int L>
__device__ __forceinline__ void ldsWrite16(float* sR, float* sI, int tid,
                                           const float ar[16], const float ai[16], int czmask) {
#pragma unroll
  for (int r = 0; r < 16; ++r) {
    int j = layoutIdx<L>(tid, r);
    float vr = ar[r], vi = ai[r];
    if (czmask) {
      float sg = (__popc((j & (j >> 1)) & czmask) & 1) ? -1.0f : 1.0f;
      vr *= sg; vi *= sg;
    }
    int a = PD(j);
    sR[a] = vr; sI[a] = vi;
  }
}

// 8-element read/write for the 512-thread kernels
template <int K>
__device__ __forceinline__ void pread8(const float* sR, const float* sI, int tid, int mode,
                                       float ar[8], float ai[8]) {
#pragma unroll
  for (int r = 0; r < 8; ++r) {
    int j = layoutIdx3<K>(tid, r);
    int a = PD(mapIdx(j, mode));
    ar[r] = sR[a]; ai[r] = sI[a];
  }
}

template <int K>
__device__ __forceinline__ void pwrite8(float* sR, float* sI, int tid,
                                        const float ar[8], const float ai[8]) {
#pragma unroll
  for (int r = 0; r < 8; ++r) {
    int a = PD(layoutIdx3<K>(tid, r));
    sR[a] = ar[r]; sI[a] = ai[r];
  }
}

// 4 U3 gates on local bits 0..3; u00 is real (= cos t/2), exploit u[1]==0.
__device__ __forceinline__ void applyU34(float ar[16], float ai[16], const float (*ut)[8]) {
#pragma unroll
  for (int b = 0; b < 4; ++b) {
    const float* u = ut[b];
    float u00r = u[0];
    float u01r = u[2], u01i = u[3];
    float u10r = u[4], u10i = u[5], u11r = u[6], u11i = u[7];
#pragma unroll
    for (int m = 0; m < 8; ++m) {
      int p0 = ((m >> b) << (b + 1)) | (m & ((1 << b) - 1));
      int p1 = p0 | (1 << b);
      float x0r = ar[p0], x0i = ai[p0], x1r = ar[p1], x1i = ai[p1];
      ar[p0] = u00r * x0r + u01r * x1r - u01i * x1i;
      ai[p0] = u00r * x0i + u01r * x1i + u01i * x1r;
      ar[p1] = u10r * x0r - u10i * x0i + u11r * x1r - u11i * x1i;
      ai[p1] = u10r * x0i + u10i * x0r + u11r * x1i + u11i * x1r;
    }
  }
}

// 3 U3 gates on local bits 0..2 (8-element state)
__device__ __forceinline__ void applyU3_3(float ar[8], float ai[8], const float (*ut)[8]) {
#pragma unroll
  for (int b = 0; b < 3; ++b) {
    const float* u = ut[b];
    float u00r = u[0];
    float u01r = u[2], u01i = u[3];
    float u10r = u[4], u10i = u[5], u11r = u[6], u11i = u[7];
#pragma unroll
    for (int m = 0; m < 4; ++m) {
      int p0 = ((m >> b) << (b + 1)) | (m & ((1 << b) - 1));
      int p1 = p0 | (1 << b);
      float x0r = ar[p0], x0i = ai[p0], x1r = ar[p1], x1i = ai[p1];
      ar[p0] = u00r * x0r + u01r * x1r - u01i * x1i;
      ai[p0] = u00r * x0i + u01r * x1i + u01i * x1r;
      ar[p1] = u10r * x0r - u10i * x0i + u11r * x1r - u11i * x1i;
      ai[p1] = u10r * x0i + u10i * x0r + u11r * x1i + u11i * x1r;
    }
  }
}

// 4 fused RY+RZ gates (16-elem state, mono path)
__device__ __forceinline__ void applyRyRz4(float ar[16], float ai[16], const float4* gt) {
#pragma unroll
  for (int b = 0; b < 4; ++b) {
    float4 g = gt[b];
    float c = g.x, s = g.y, zr = g.z, zi = g.w;
#pragma unroll
    for (int m = 0; m < 8; ++m) {
      int p0 = ((m >> b) << (b + 1)) | (m & ((1 << b) - 1));
      int p1 = p0 | (1 << b);
      float x0r = ar[p0], x0i = ai[p0], x1r = ar[p1], x1i = ai[p1];
      float n0r = c * x0r - s * x1r;
      float n0i = c * x0i - s * x1i;
      float wr  = s * x0r + c * x1r;
      float wi  = s * x0i + c * x1i;
      ar[p0] = n0r;              ai[p0] = n0i;
      ar[p1] = wr * zr - wi * zi; ai[p1] = wr * zi + wi * zr;
    }
  }
}

// 3 fused RY+RZ gates (8-elem state, proj_split 512-thread path)
__device__ __forceinline__ void applyRyRz3(float ar[8], float ai[8], const float4* gt) {
#pragma unroll
  for (int b = 0; b < 3; ++b) {
    float4 g = gt[b];
    float c = g.x, s = g.y, zr = g.z, zi = g.w;
#pragma unroll
    for (int m = 0; m < 4; ++m) {
      int p0 = ((m >> b) << (b + 1)) | (m & ((1 << b) - 1));
      int p1 = p0 | (1 << b);
      float x0r = ar[p0], x0i = ai[p0], x1r = ar[p1], x1i = ai[p1];
      float n0r = c * x0r - s * x1r;
      float n0i = c * x0i - s * x1i;
      float wr  = s * x0r + c * x1r;
      float wi  = s * x0i + c * x1i;
      ar[p0] = n0r;              ai[p0] = n0i;
      ar[p1] = wr * zr - wi * zi; ai[p1] = wr * zi + wi * zr;
    }
  }
}

template <int L>
__device__ __forceinline__ void encPass(float* sR, float* sI, int tid, int mode,
                                        const float (*ut)[8], int czmask) {
  float ar[16], ai[16];
  ldsRead16<L>(sR, sI, tid, mode, ar, ai);
  if (mode != 0) __syncthreads();
  applyU34(ar, ai, ut);
  ldsWrite16<L>(sR, sI, tid, ar, ai, czmask);
  __syncthreads();
}

// enc 512-thread pass
template <int K>
__device__ __forceinline__ void encPass3(float* sR, float* sI, int tid, int mode,
                                         const float (*ut)[8], int czmask) {
  float ar[8], ai[8];
  pread8<K>(sR, sI, tid, mode, ar, ai);
  if (mode != 0) __syncthreads();
  applyU3_3(ar, ai, ut);
#pragma unroll
  for (int r = 0; r < 8; ++r) {
    int j = layoutIdx3<K>(tid, r);
    float vr = ar[r], vi = ai[r];
    if (czmask) {
      float sg = (__popc((j & (j >> 1)) & czmask) & 1) ? -1.0f : 1.0f;
      vr *= sg; vi *= sg;
    }
    int a = PD(j);
    sR[a] = vr; sI[a] = vi;
  }
  __syncthreads();
}

// Final projection pass (mono path, L2 layout)
__device__ __forceinline__ void projFinal(const float* sR, const float* sI, int tid,
                                          const float4* gt, float feat[12]) {
  float ar[16], ai[16];
#pragma unroll
  for (int r = 0; r < 16; ++r) {
    int a = PD((r << 8) | tid);
    ar[r] = sR[a]; ai[r] = sI[a];
  }
  applyRyRz4(ar, ai, gt);
  float sp = 0.f, f0 = 0.f, f1 = 0.f, f2 = 0.f, f3 = 0.f;
  int pt = __popc(tid) & 1;
#pragma unroll
  for (int r = 0; r < 16; ++r) {
    float p = ar[r] * ar[r] + ai[r] * ai[r];
    sp += p;
    int tr = r ^ (r << 1); tr ^= (tr << 2);
    f0 += ((pt ^ ((tr >> 3) & 1)) ? -p : p);
    f1 += ((pt ^ ((tr >> 2) & 1)) ? -p : p);
    f2 += ((pt ^ ((tr >> 1) & 1)) ? -p : p);
    f3 += ((pt ^ (tr & 1)) ? -p : p);
  }
  feat[0] = f0; feat[1] = f1; feat[2] = f2; feat[3] = f3;
  int tt = tid ^ (tid << 1); tt ^= (tt << 2); tt ^= (tt << 4);
#pragma unroll
  for (int q = 4; q < 12; ++q)
    feat[q] = ((tt >> (11 - q)) & 1) ? -sp : sp;
}

__device__ __forceinline__ float waveReduce(float v) {
#pragma unroll
  for (int off = 32; off; off >>= 1) v += __shfl_xor(v, off, 64);
  return v;
}

// ---- shared setup helpers ----

__device__ __forceinline__ void buildQtab(float4* qtab, int tid, float x) {
  const float PI = 3.14159265358979323846f;
  const float RS2 = 0.70710678118654752440f;
  if (tid < 12) {
    int i = tid;
    float th = x * PI * (float)(i + 1) / 12.0f;
    float ph = x * PI / (float)(i + 1);
    float s, c;  sincosf(0.5f * th, &s, &c);
    float zi, zr; sincosf(0.5f * ph, &zi, &zr);
    float k0 = (c - s) * RS2, k1 = (c + s) * RS2;
    qtab[i] = make_float4(k0 * zr, -k0 * zi, k1 * zr, k1 * zi);
  }
}

__device__ __forceinline__ void buildUtab(float (*utab)[8], int tid, const float* resp) {
  if (tid >= 64 && tid < 100) {
    int i = tid - 64;
    const float* rp = resp + i * 3;
    float st, ct;  sincosf(0.5f * rp[0], &st, &ct);
    float sp2, cp; sincosf(rp[1], &sp2, &cp);
    float sl, cl;  sincosf(rp[2], &sl, &cl);
    float spl, cpl; sincosf(rp[1] + rp[2], &spl, &cpl);
    float* u = utab[i];
    u[0] = ct;       u[1] = 0.0f;
    u[2] = -cl * st; u[3] = -sl * st;
    u[4] = cp * st;  u[5] = sp2 * st;
    u[6] = cpl * ct; u[7] = spl * ct;
  }
}

// 256-thread product init (mono path)
__device__ __forceinline__ void initProduct(float* sRe, float* sIm, int tid, const float4* qtab) {
  float pr, pi;
  {
    float4 g = qtab[4];
    int sb = tid & 1;
    pr = sb ? g.z : g.x; pi = sb ? g.w : g.y;
  }
#pragma unroll
  for (int q = 5; q < 12; ++q) {
    float4 g = qtab[q];
    int sb = (tid >> (q - 4)) & 1;
    float fr = sb ? g.z : g.x, fi = sb ? g.w : g.y;
    float nr = pr * fr - pi * fi;
    pi = pr * fi + pi * fr; pr = nr;
  }
  float4 g0 = qtab[0], g1 = qtab[1], g2 = qtab[2], g3 = qtab[3];
  float c01r[4], c01i[4], c23r[4], c23i[4];
#pragma unroll
  for (int i2 = 0; i2 < 4; ++i2) {
    float f0r = (i2 & 1) ? g0.z : g0.x, f0i = (i2 & 1) ? g0.w : g0.y;
    float f1r = (i2 & 2) ? g1.z : g1.x, f1i = (i2 & 2) ? g1.w : g1.y;
    c01r[i2] = f0r * f1r - f0i * f1i; c01i[i2] = f0r * f1i + f0i * f1r;
    float f2r = (i2 & 1) ? g2.z : g2.x, f2i = (i2 & 1) ? g2.w : g2.y;
    float f3r = (i2 & 2) ? g3.z : g3.x, f3i = (i2 & 2) ? g3.w : g3.y;
    c23r[i2] = f2r * f3r - f2i * f3i; c23i[i2] = f2r * f3i + f2i * f3r;
  }
#pragma unroll
  for (int r = 0; r < 16; ++r) {
    float lr = c01r[r & 3] * c23r[r >> 2] - c01i[r & 3] * c23i[r >> 2];
    float li = c01r[r & 3] * c23i[r >> 2] + c01i[r & 3] * c23r[r >> 2];
    int a = PD((tid << 4) | r);
    sRe[a] = pr * lr - pi * li;
    sIm[a] = pr * li + pi * lr;
  }
}

// 512-thread product init (enc path)
__device__ __forceinline__ void initProduct3(float* sRe, float* sIm, int tid, const float4* qtab) {
  float pr, pi;
  {
    float4 g = qtab[3];
    int sb = tid & 1;
    pr = sb ? g.z : g.x; pi = sb ? g.w : g.y;
  }
#pragma unroll
  for (int q = 4; q < 12; ++q) {
    float4 g = qtab[q];
    int sb = (tid >> (q - 3)) & 1;
    float fr = sb ? g.z : g.x, fi = sb ? g.w : g.y;
    float nr = pr * fr - pi * fi;
    pi = pr * fi + pi * fr; pr = nr;
  }
  float4 g0 = qtab[0], g1 = qtab[1], g2 = qtab[2];
  float c01r[4], c01i[4];
#pragma unroll
  for (int i2 = 0; i2 < 4; ++i2) {
    float f0r = (i2 & 1) ? g0.z : g0.x, f0i = (i2 & 1) ? g0.w : g0.y;
    float f1r = (i2 & 2) ? g1.z : g1.x, f1i = (i2 & 2) ? g1.w : g1.y;
    c01r[i2] = f0r * f1r - f0i * f1i; c01i[i2] = f0r * f1i + f0i * f1r;
  }
#pragma unroll
  for (int r = 0; r < 8; ++r) {
    float f2r = (r & 4) ? g2.z : g2.x, f2i = (r & 4) ? g2.w : g2.y;
    float lr = c01r[r & 3] * f2r - c01i[r & 3] * f2i;
    float li = c01r[r & 3] * f2i + c01i[r & 3] * f2r;
    int a = PD((tid << 3) | r);
    sRe[a] = pr * lr - pi * li;
    sIm[a] = pr * li + pi * lr;
  }
}

__device__ __forceinline__ void buildPtab(float4* ptab, int tid, const float* hp) {
  if (tid < 24) {
    int k = tid * 2;
    float s, c;  sincosf(0.5f * hp[k], &s, &c);
    float zi, zr; sincosf(hp[k + 1], &zi, &zr);
    ptab[tid] = make_float4(c, s, zr, zi);
  }
}

// ================= SPLIT PATH =================

// Kernel A: encode -> global. 512 threads/block, 8 elem/thread, 3-bit locals.
__global__ __launch_bounds__(512, 4) void enc_kernel(
    const float* __restrict__ seq, const float* __restrict__ resp,
    float* __restrict__ wsStates) {
  __shared__ float sRe[PADDED], sIm[PADDED];
  __shared__ float4 qtab[12];
  __shared__ float utab[36][8];

  const int tid = threadIdx.x;
  const int blk = blockIdx.x;
  const float x = seq[blk];

  buildQtab(qtab, tid, x);
  buildUtab(utab, tid, resp);
  __syncthreads();

  initProduct3(sRe, sIm, tid, qtab);
  __syncthreads();

  // layer 0: q0-2 (ladder+ring fold on read), q3-5, q6-8, q9-11 + CZ(0x555)
  encPass3<0>(sRe, sIm, tid, 1, &utab[0], 0);
  encPass3<1>(sRe, sIm, tid, 0, &utab[3], 0);
  encPass3<2>(sRe, sIm, tid, 0, &utab[6], 0);
  encPass3<3>(sRe, sIm, tid, 0, &utab[9], 0x555);
  // layer 1: CX_LONG fold on first read; CZ(0x2AA)
  encPass3<0>(sRe, sIm, tid, 2, &utab[12], 0);
  encPass3<1>(sRe, sIm, tid, 0, &utab[15], 0);
  encPass3<2>(sRe, sIm, tid, 0, &utab[18], 0);
  encPass3<3>(sRe, sIm, tid, 0, &utab[21], 0x2AA);
  // layer 2: CX_LONG fold on first read
  encPass3<0>(sRe, sIm, tid, 2, &utab[24], 0);
  encPass3<1>(sRe, sIm, tid, 0, &utab[27], 0);
  encPass3<2>(sRe, sIm, tid, 0, &utab[30], 0);

  // final: q9-11 (layer 2), CZ(0x555) + CX_LONG folded into store index
  {
    float ar[8], ai[8];
#pragma unroll
    for (int r = 0; r < 8; ++r) {
      int a = PD((r << 9) | tid);
      ar[r] = sRe[a]; ai[r] = sIm[a];
    }
    applyU3_3(ar, ai, &utab[33]);
    float* gR = wsStates + (size_t)blk * 8192;
    float* gI = gR + 4096;
#pragma unroll
    for (int r = 0; r < 8; ++r) {
      int j = (r << 9) | tid;
      float sg = (__popc((j & (j >> 1)) & 0x555) & 1) ? -1.0f : 1.0f;
      int g = j ^ ((j & 1) << 11);  // involution
      gR[g] = sg * ar[r];
      gI[g] = sg * ai[r];
    }
  }
}

// Kernel B: one projection per block. 512 threads, 8 elem/thread, full-state
// LDS (34KB), 3-bit-local passes P0..P7, ladder folded into P4's read and the
// trailing ladder into measurement signs (px rule: feat[q] sign = bit (11-q)
// of the low-prefix-XOR of element index j).
__global__ __launch_bounds__(512, 8) void proj_split(
    const float* __restrict__ wsStates, const float* __restrict__ hparams,
    float* __restrict__ featBase) {
  __shared__ float sRe[PADDED], sIm[PADDED];
  __shared__ float4 ptab[24];
  __shared__ float red[8][12];

  const int tid = threadIdx.x;
  const int bid = blockIdx.x;
  int h, which, s;
  if (bid < 2048) { s = bid >> 2; int pp = bid & 3; h = pp >> 1; which = 1 + (pp & 1); }
  else            { int i = bid - 2048; h = i & 1; s = (((i >> 1) << 6) | 63); which = 0; }
  const int b = s >> 6, t = s & 63;

  buildPtab(ptab, tid, hparams + (h * 3 + which) * 48);

  // coalesced load: thread owns j = 8*tid .. 8*tid+7 (L0)
  float ar[8], ai[8];
  {
    const float4* pR = (const float4*)(wsStates + (size_t)s * 8192 + (tid << 3));
    const float4* pI = (const float4*)(wsStates + (size_t)s * 8192 + 4096 + (tid << 3));
    float4 v0 = pR[0], v1 = pR[1], w0 = pI[0], w1 = pI[1];
    ar[0] = v0.x; ar[1] = v0.y; ar[2] = v0.z; ar[3] = v0.w;
    ar[4] = v1.x; ar[5] = v1.y; ar[6] = v1.z; ar[7] = v1.w;
    ai[0] = w0.x; ai[1] = w0.y; ai[2] = w0.z; ai[3] = w0.w;
    ai[4] = w1.x; ai[5] = w1.y; ai[6] = w1.z; ai[7] = w1.w;
  }
  __syncthreads();  // ptab ready

  // P0: layer-0 q0-2 on regs (L0)
  applyRyRz3(ar, ai, &ptab[0]);
  pwrite8<0>(sRe, sIm, tid, ar, ai);
  __syncthreads();
  // P1: q3-5
  pread8<1>(sRe, sIm, tid, 0, ar, ai);
  applyRyRz3(ar, ai, &ptab[3]);
  pwrite8<1>(sRe, sIm, tid, ar, ai);
  __syncthreads();
  // P2: q6-8
  pread8<2>(sRe, sIm, tid, 0, ar, ai);
  applyRyRz3(ar, ai, &ptab[6]);
  pwrite8<2>(sRe, sIm, tid, ar, ai);
  __syncthreads();
  // P3: q9-11
  pread8<3>(sRe, sIm, tid, 0, ar, ai);
  applyRyRz3(ar, ai, &ptab[9]);
  pwrite8<3>(sRe, sIm, tid, ar, ai);
  __syncthreads();
  // P4: layer-0 ladder fold on read, then layer-1 q0-2
  pread8<0>(sRe, sIm, tid, 3, ar, ai);
  __syncthreads();  // cross-thread read set: drain before overwriting
  applyRyRz3(ar, ai, &ptab[12]);
  pwrite8<0>(sRe, sIm, tid, ar, ai);
  __syncthreads();
  // P5: q3-5
  pread8<1>(sRe, sIm, tid, 0, ar, ai);
  applyRyRz3(ar, ai, &ptab[15]);
  pwrite8<1>(sRe, sIm, tid, ar, ai);
  __syncthreads();
  // P6: q6-8
  pread8<2>(sRe, sIm, tid, 0, ar, ai);
  applyRyRz3(ar, ai, &ptab[18]);
  pwrite8<2>(sRe, sIm, tid, ar, ai);
  __syncthreads();
  // P7: q9-11 + measurement with trailing-ladder fold.
  // Element j = (r<<9) | tid. Sign for feature q = bit (11-q) of low-prefix-XOR(j):
  //   q=0: ptid^parity(r); q=1: ptid^r0^r1; q=2: ptid^r0; q=3: ptid;
  //   q>=4: parity(tid & ((1<<(12-q))-1)).
  pread8<3>(sRe, sIm, tid, 0, ar, ai);
  applyRyRz3(ar, ai, &ptab[21]);

  float p[8];
#pragma unroll
  for (int r = 0; r < 8; ++r) p[r] = ar[r] * ar[r] + ai[r] * ai[r];
  float S  = ((p[0] + p[1]) + (p[2] + p[3])) + ((p[4] + p[5]) + (p[6] + p[7]));
  float A1 = ((p[0] - p[1]) + (p[2] - p[3])) + ((p[4] - p[5]) + (p[6] - p[7]));  // (-1)^r0
  float A2 = ((p[0] - p[1]) - (p[2] - p[3])) + ((p[4] - p[5]) - (p[6] - p[7]));  // (-1)^(r0^r1)
  float A3 = ((p[0] - p[1]) - (p[2] - p[3])) - ((p[4] - p[5]) - (p[6] - p[7]));  // (-1)^parity(r)
  int ptid = __popc(tid) & 1;
  float sgn = ptid ? -1.f : 1.f;
  float feat[12];
  feat[0]  = sgn * A3;
  feat[1]  = sgn * A2;
  feat[2]  = sgn * A1;
  feat[3]  = sgn * S;
  feat[4]  = (__popc(tid & 0xFF) & 1) ? -S : S;
  feat[5]  = (__popc(tid & 0x7F) & 1) ? -S : S;
  feat[6]  = (__popc(tid & 0x3F) & 1) ? -S : S;
  feat[7]  = (__popc(tid & 0x1F) & 1) ? -S : S;
  feat[8]  = (__popc(tid & 0x0F) & 1) ? -S : S;
  feat[9]  = (__popc(tid & 0x07) & 1) ? -S : S;
  feat[10] = (__popc(tid & 0x03) & 1) ? -S : S;
  feat[11] = (tid & 1) ? -S : S;

#pragma unroll
  for (int q = 0; q < 12; ++q) feat[q] = waveReduce(feat[q]);
  int wid = tid >> 6;
  if ((tid & 63) == 0) {
#pragma unroll
    for (int q = 0; q < 12; ++q) red[wid][q] = feat[q];
  }
  __syncthreads();
  if (tid < 12) {
    float v = ((red[0][tid] + red[1][tid]) + (red[2][tid] + red[3][tid]))
            + ((red[4][tid] + red[5][tid]) + (red[6][tid] + red[7][tid]));
    float* dst;
    if (which == 1)      dst = featBase + (((h << 3) + b) * 64 + t) * 12;
    else if (which == 2) dst = featBase + 12288 + (((h << 3) + b) * 64 + t) * 12;
    else                 dst = featBase + 24576 + ((h << 3) + b) * 12;
    dst[tid] = v;
  }
}

// ================= MONOLITHIC FALLBACK =================

__global__ __launch_bounds__(256, 2) void qstates_mono(
    const float* __restrict__ seq, const float* __restrict__ resp,
    const float* __restrict__ hparams, float* __restrict__ featBase) {
  __shared__ float sRe[PADDED], sIm[PADDED];
  __shared__ float4 qtab[12];
  __shared__ float utab[36][8];
  __shared__ float4 ptab[24];
  __shared__ float red[4][12];

  const int tid = threadIdx.x;
  const int blk = blockIdx.x;
  const int b = blk >> 6;
  const int t = blk & 63;
  const float x = seq[blk];

  buildQtab(qtab, tid, x);
  buildUtab(utab, tid, resp);
  __syncthreads();
  initProduct(sRe, sIm, tid, qtab);
  __syncthreads();

  for (int l = 0; l < 3; ++l) {
    int czm = (l & 1) ? 0x2AA : 0x555;
    encPass<0>(sRe, sIm, tid, (l == 0) ? 1 : 2, &utab[l * 12], 0);
    encPass<1>(sRe, sIm, tid, 0, &utab[l * 12 + 4], 0);
    encPass<2>(sRe, sIm, tid, 0, &utab[l * 12 + 8], czm);
  }

  float encR[16], encI[16];
#pragma unroll
  for (int r = 0; r < 16; ++r) {
    int j = (tid << 4) | r;
    int a = PD(j ^ ((j & 1) << 11));
    encR[r] = sRe[a]; encI[r] = sIm[a];
  }

  const int nproj = (t == 63) ? 6 : 4;
  for (int pj = 0; pj < nproj; ++pj) {
    int h, which;
    if (pj < 4) { h = pj >> 1; which = (pj & 1) ? 2 : 1; }
    else        { h = pj - 4;  which = 0; }
    buildPtab(ptab, tid, hparams + (h * 3 + which) * 48);
    __syncthreads();

    float ar[16], ai[16];
#pragma unroll
    for (int r = 0; r < 16; ++r) { ar[r] = encR[r]; ai[r] = encI[r]; }
    applyRyRz4(ar, ai, &ptab[0]);
    ldsWrite16<0>(sRe, sIm, tid, ar, ai, 0);
    __syncthreads();
    {
      float br[16], bi[16];
      ldsRead16<1>(sRe, sIm, tid, 0, br, bi);
      applyRyRz4(br, bi, &ptab[4]);
      ldsWrite16<1>(sRe, sIm, tid, br, bi, 0);
      __syncthreads();
      ldsRead16<2>(sRe, sIm, tid, 0, br, bi);
      applyRyRz4(br, bi, &ptab[8]);
      ldsWrite16<2>(sRe, sIm, tid, br, bi, 0);
      __syncthreads();
      ldsRead16<0>(sRe, sIm, tid, 3, br, bi);
      __syncthreads();
      applyRyRz4(br, bi, &ptab[12]);
      ldsWrite16<0>(sRe, sIm, tid, br, bi, 0);
      __syncthreads();
      ldsRead16<1>(sRe, sIm, tid, 0, br, bi);
      applyRyRz4(br, bi, &ptab[16]);
      ldsWrite16<1>(sRe, sIm, tid, br, bi, 0);
      __syncthreads();
    }

    float feat[12];
    projFinal(sRe, sIm, tid, &ptab[20], feat);
#pragma unroll
    for (int q = 0; q < 12; ++q) feat[q] = waveReduce(feat[q]);
    int wid = tid >> 6;
    if ((tid & 63) == 0) {
#pragma unroll
      for (int q = 0; q < 12; ++q) red[wid][q] = feat[q];
    }
    __syncthreads();
    if (tid < 12) {
      float v = red[0][tid] + red[1][tid] + red[2][tid] + red[3][tid];
      float* dst;
      if (which == 1)      dst = featBase + (((h << 3) + b) * 64 + t) * 12;
      else if (which == 2) dst = featBase + 12288 + (((h << 3) + b) * 64 + t) * 12;
      else                 dst = featBase + 24576 + ((h << 3) + b) * 12;
      dst[tid] = v;
    }
    __syncthreads();
  }
}

// ================= HEAD =================

__global__ __launch_bounds__(64) void qhead_kernel(
    const float* __restrict__ featBase,
    const float* __restrict__ W1, const float* __restrict__ b1,
    const float* __restrict__ W2, const float* __restrict__ b2,
    float* __restrict__ out) {
  __shared__ float feats[24];
  __shared__ float hdn[48];
  const int b = blockIdx.x;
  const int lane = threadIdx.x;
  const float* Kf = featBase;
  const float* Vf = featBase + 12288;
  const float* Qf = featBase + 24576;
  for (int h = 0; h < 2; ++h) {
    const float* q  = Qf + ((h << 3) + b) * 12;
    const float* kr = Kf + ((((h << 3) + b) << 6) + lane) * 12;
    float dot = 0.f;
#pragma unroll
    for (int d = 0; d < 12; ++d) dot += q[d] * kr[d];
    dot *= 0.288675134594812882f;
    float mx = dot;
#pragma unroll
    for (int off = 32; off; off >>= 1) mx = fmaxf(mx, __shfl_xor(mx, off, 64));
    float e = expf(dot - mx);
    float se = e;
#pragma unroll
    for (int off = 32; off; off >>= 1) se += __shfl_xor(se, off, 64);
    float a = e / se;
    const float* vr = Vf + ((((h << 3) + b) << 6) + lane) * 12;
#pragma unroll
    for (int d = 0; d < 12; ++d) {
      float v = a * vr[d];
#pragma unroll
      for (int off = 32; off; off >>= 1) v += __shfl_xor(v, off, 64);
      if (lane == 0) feats[h * 12 + d] = v;
    }
  }
  __syncthreads();
  if (lane < 48) {
    float acc = b1[lane];
#pragma unroll
    for (int f = 0; f < 24; ++f) acc += feats[f] * W1[f * 48 + lane];
    hdn[lane] = 0.5f * acc * (1.0f + erff(acc * 0.70710678118654752440f));
  }
  __syncthreads();
  if (lane < 4) {
    float acc = b2[lane];
#pragma unroll
    for (int k = 0; k < 48; ++k) acc += hdn[k] * W2[k * 4 + lane];
    out[(b << 2) | lane] = acc;
  }
}

extern "C" void kernel_launch(void* const* d_in, const int* in_sizes, int n_in,
                              void* d_out, int out_size, void* d_ws, size_t ws_size,
                              hipStream_t stream) {
  const float* seq     = (const float*)d_in[0];
  const float* resp    = (const float*)d_in[1];
  const float* hparams = (const float*)d_in[2];
  const float* W1      = (const float*)d_in[3];
  const float* b1      = (const float*)d_in[4];
  const float* W2      = (const float*)d_in[5];
  const float* b2      = (const float*)d_in[6];
  float* out = (float*)d_out;
  float* ws  = (float*)d_ws;

  const size_t needSplit = ((size_t)512 * 8192 + 24768) * sizeof(float);
  if (ws_size >= needSplit) {
    float* wsStates = ws;
    float* featBase = ws + (size_t)512 * 8192;
    hipLaunchKernelGGL(enc_kernel, dim3(512), dim3(512), 0, stream, seq, resp, wsStates);
    hipLaunchKernelGGL(proj_split, dim3(2064), dim3(512), 0, stream, wsStates, hparams, featBase);
    hipLaunchKernelGGL(qhead_kernel, dim3(8), dim3(64), 0, stream, featBase, W1, b1, W2, b2, out);
  } else {
    hipLaunchKernelGGL(qstates_mono, dim3(512), dim3(256), 0, stream, seq, resp, hparams, ws);
    hipLaunchKernelGGL(qhead_kernel, dim3(8), dim3(64), 0, stream, ws, W1, b1, W2, b2, out);
  }
}